// Round 4
// baseline (159.177 us; speedup 1.0000x reference)
//
#include <hip/hip_runtime.h>

// PolynomialAttn: B=2,H=16,S=2048,D=64, degree=2, eps=1e-4, fp32 in/out.
// v4: 32x32x16 MFMA; X^T = K*Q^T; PV as O^T = V^T*X^T with the C->B operand
// transform done IN REGISTERS via v_permlane32_swap_b32 (no X LDS round-trip).
// Double-buffered K/V LDS, register prefetch, one barrier/tile. Epilogue
// transposes O^T through LDS for coalesced stores. Prepass unchanged.

#define S_LEN 2048
#define DH    64
#define BQ    128
#define BK    64
#define LSTR  72        // LDS row stride in ushorts (pad 8: 16B-aligned)
#define EPSTR 68        // epilogue fp32 transpose stride
#define PSTR  65        // prepass transpose LDS stride
#define BH_N  32        // B*H
#define PER_BH (S_LEN * DH)   // 131072 elems
#define NT    (S_LEN / BK)    // 32 KV tiles

typedef __bf16 bf16x8 __attribute__((ext_vector_type(8)));
typedef __bf16 bf16x2 __attribute__((ext_vector_type(2)));
typedef float  f32x4  __attribute__((ext_vector_type(4)));
typedef float  f32x16 __attribute__((ext_vector_type(16)));
typedef unsigned int uivec2 __attribute__((ext_vector_type(2)));

__device__ __forceinline__ unsigned short f2bf(float f) {
    union { float f; unsigned int u; } x; x.f = f;
    unsigned int u = x.u;
    return (unsigned short)((u + 0x7fffu + ((u >> 16) & 1u)) >> 16);  // RNE
}

__device__ __forceinline__ unsigned int pack2bf(float lo, float hi) {
#if __has_builtin(__builtin_amdgcn_cvt_pk_bf16_f32)
    bf16x2 p = __builtin_amdgcn_cvt_pk_bf16_f32(lo, hi);
    union { bf16x2 v; unsigned int u; } c; c.v = p;
    return c.u;
#else
    return (unsigned int)f2bf(lo) | ((unsigned int)f2bf(hi) << 16);
#endif
}

// swap a's upper 32 lanes with b's lower 32 lanes:
// a' = {a[lanes 0-31], b[lanes 0-31]}, b' = {a[lanes 32-63], b[lanes 32-63]}
__device__ __forceinline__ void pl32swap(unsigned int& a, unsigned int& b) {
#if __has_builtin(__builtin_amdgcn_permlane32_swap)
    uivec2 r = __builtin_amdgcn_permlane32_swap(a, b, false, false);
    a = r[0]; b = r[1];
#else
    asm("v_permlane32_swap_b32 %0, %1" : "+v"(a), "+v"(b));
#endif
}

// ---------------- fused prepass: K fp32->bf16 copy + V fp32 -> V^T bf16 ----------------
__global__ __launch_bounds__(256)
void prepass_kernel(const float* __restrict__ kg, const float* __restrict__ vg,
                    unsigned short* __restrict__ kbf, unsigned short* __restrict__ vt)
{
    __shared__ unsigned short Ls[64 * PSTR];
    const int tid = threadIdx.x;
    const int bh  = blockIdx.y;
    const int t0  = blockIdx.x * 64;
    const size_t base = (size_t)bh * PER_BH + (size_t)t0 * DH;

    {
        const float4* src = (const float4*)(kg + base + (size_t)tid * 16);
        float4 a = src[0], b = src[1], c = src[2], d = src[3];
        union { unsigned short h[8]; uint4 v; } u0, u1;
        u0.h[0]=f2bf(a.x); u0.h[1]=f2bf(a.y); u0.h[2]=f2bf(a.z); u0.h[3]=f2bf(a.w);
        u0.h[4]=f2bf(b.x); u0.h[5]=f2bf(b.y); u0.h[6]=f2bf(b.z); u0.h[7]=f2bf(b.w);
        u1.h[0]=f2bf(c.x); u1.h[1]=f2bf(c.y); u1.h[2]=f2bf(c.z); u1.h[3]=f2bf(c.w);
        u1.h[4]=f2bf(d.x); u1.h[5]=f2bf(d.y); u1.h[6]=f2bf(d.z); u1.h[7]=f2bf(d.w);
        uint4* dst = (uint4*)(kbf + base + (size_t)tid * 16);
        dst[0] = u0.v; dst[1] = u1.v;
    }

    const float* vb = vg + base;
    #pragma unroll
    for (int r = 0; r < 4; ++r) {
        int idx = r * 256 + tid;
        int row = idx >> 4, c4 = idx & 15;
        float4 f = ((const float4*)vb)[idx];
        unsigned short* p = &Ls[row * PSTR + c4 * 4];
        p[0] = f2bf(f.x); p[1] = f2bf(f.y); p[2] = f2bf(f.z); p[3] = f2bf(f.w);
    }
    __syncthreads();
    #pragma unroll
    for (int r = 0; r < 2; ++r) {
        int idx = r * 256 + tid;
        int d = idx >> 3, j8 = idx & 7;
        union { unsigned short h[8]; uint4 v; } u;
        #pragma unroll
        for (int jj = 0; jj < 8; ++jj) u.h[jj] = Ls[(j8 * 8 + jj) * PSTR + d];
        *(uint4*)(vt + (size_t)bh * PER_BH + (size_t)d * S_LEN + t0 + j8 * 8) = u.v;
    }
}

// ---------------- main kernel ----------------
__global__ __launch_bounds__(256, 2)
void poly_attn_main(const float* __restrict__ qg,
                    const unsigned short* __restrict__ kbf,
                    const unsigned short* __restrict__ vtbf,
                    float* __restrict__ og)
{
    // layout: [Ks buf0 | Ks buf1 | Vts buf0 | Vts buf1], each 64*LSTR ushorts.
    // Reused at epilogue as per-wave fp32 transpose buffers.
    __shared__ __align__(16) unsigned short smem[4 * 64 * LSTR];
    #define KS_BASE(b)  ((b) * 64 * LSTR)
    #define VTS_BASE(b) ((2 + (b)) * 64 * LSTR)

    const int tid  = threadIdx.x;
    const int lane = tid & 63;
    const int w    = tid >> 6;        // wave id: owns Q rows [32w, 32w+32)
    const int l31  = lane & 31;       // i within wave strip / m within A-frag
    const int h    = lane >> 5;       // lane half

    const int bh = blockIdx.y;
    const int q0 = blockIdx.x * BQ;

    const float* qb = qg + ((size_t)bh * S_LEN + q0) * DH;
    const unsigned short* kb  = kbf  + (size_t)bh * PER_BH;
    const unsigned short* vtb = vtbf + (size_t)bh * PER_BH;
    float* ob = og + ((size_t)bh * S_LEN + q0) * DH;

    // ---- preload Q B-fragments: lane holds Q[32w+l31][16ks + 8h + 0..7] ----
    bf16x8 qfrag[4];
    #pragma unroll
    for (int ks = 0; ks < 4; ++ks) {
        const float* qp = qb + (32 * w + l31) * DH + ks * 16 + h * 8;
        float4 f0 = *(const float4*)qp;
        float4 f1 = *(const float4*)(qp + 4);
        union { unsigned int d[4]; bf16x8 v; } u;
        u.d[0] = pack2bf(f0.x, f0.y);
        u.d[1] = pack2bf(f0.z, f0.w);
        u.d[2] = pack2bf(f1.x, f1.y);
        u.d[3] = pack2bf(f1.z, f1.w);
        qfrag[ks] = u.v;
    }

    f32x16 oacc[2];   // O^T[d = mt*32 + (reg&3)+8*(reg>>2)+4h][i = l31]
    #pragma unroll
    for (int mt = 0; mt < 2; ++mt)
        #pragma unroll
        for (int r = 0; r < 16; ++r) oacc[mt][r] = 0.f;
    float dsum = 0.f;   // per-lane partial denominator for column i = l31

    // staging: 256 threads move 64x64 bf16 K + 64x64 V^T per tile, 16B chunks
    const int srow = tid >> 3;        // 0..31 (+32 on second pass)
    const int sc8  = tid & 7;

    // ---- prologue: load tile 0, stage into buffer 0 ----
    uint4 kreg[2], vreg[2];
    #pragma unroll
    for (int it = 0; it < 2; ++it) {
        int row = srow + it * 32;
        kreg[it] = *(const uint4*)(kb + (size_t)row * DH + sc8 * 8);
        vreg[it] = *(const uint4*)(vtb + (size_t)row * S_LEN + sc8 * 8);
    }
    #pragma unroll
    for (int it = 0; it < 2; ++it) {
        int row = srow + it * 32;
        *(uint4*)&smem[KS_BASE(0)  + row * LSTR + sc8 * 8] = kreg[it];
        *(uint4*)&smem[VTS_BASE(0) + row * LSTR + sc8 * 8] = vreg[it];
    }
    __syncthreads();

    for (int t = 0; t < NT; ++t) {
        const int cur = t & 1;
        if (t + 1 < NT) {
            const int t0n = (t + 1) * BK;
            #pragma unroll
            for (int it = 0; it < 2; ++it) {
                int row = srow + it * 32;
                kreg[it] = *(const uint4*)(kb + (size_t)(t0n + row) * DH + sc8 * 8);
                vreg[it] = *(const uint4*)(vtb + (size_t)row * S_LEN + t0n + sc8 * 8);
            }
        }

        // ---- X^T = K Q^T (32x32x16), then square/pack/permlane into B-frags ----
        unsigned int bfrag[4][4];   // [ks][dword]; B: X^2[j=16ks+8h+b][i=l31]
        #pragma unroll
        for (int jt = 0; jt < 2; ++jt) {
            f32x16 acc;
            #pragma unroll
            for (int r = 0; r < 16; ++r) acc[r] = 0.f;
            #pragma unroll
            for (int ks = 0; ks < 4; ++ks) {
                // A-frag: K[jt*32 + l31][16ks + 8h + 0..7]
                bf16x8 kf = *(const bf16x8*)&smem[KS_BASE(cur) + (jt * 32 + l31) * LSTR + ks * 16 + h * 8];
                acc = __builtin_amdgcn_mfma_f32_32x32x16_bf16(kf, qfrag[ks], acc, 0, 0, 0);
            }
            // acc reg r+4g holds X^T[j = jt*32 + r + 8g + 4h][i=l31]
            unsigned int pk[4][2];
            #pragma unroll
            for (int g = 0; g < 4; ++g) {
                float x0 = acc[4*g+0], x1 = acc[4*g+1], x2 = acc[4*g+2], x3 = acc[4*g+3];
                x0 *= x0; x1 *= x1; x2 *= x2; x3 *= x3;
                dsum += (x0 + x1) + (x2 + x3);
                pk[g][0] = pack2bf(x0, x1);
                pk[g][1] = pack2bf(x2, x3);
            }
            // B-frag for ks = jt*2 + e needs source groups g = 2e (dest h=0) and
            // g = 2e+1 (dest h=1); permlane32_swap produces both frag halves.
            #pragma unroll
            for (int e = 0; e < 2; ++e) {
                unsigned int a0 = pk[2*e][0], b0 = pk[2*e+1][0];
                unsigned int a1 = pk[2*e][1], b1 = pk[2*e+1][1];
                pl32swap(a0, b0);
                pl32swap(a1, b1);
                const int ks = jt * 2 + e;
                bfrag[ks][0] = a0; bfrag[ks][1] = a1;   // b=0..3  (from lanes 0-31 sources)
                bfrag[ks][2] = b0; bfrag[ks][3] = b1;   // b=4..7  (from lanes 32-63 sources)
            }
        }

        // ---- O^T += V^T X^2T (32x32x16): A = V^T from LDS, B = bfrag regs ----
        #pragma unroll
        for (int mt = 0; mt < 2; ++mt) {
            #pragma unroll
            for (int ks = 0; ks < 4; ++ks) {
                bf16x8 vf = *(const bf16x8*)&smem[VTS_BASE(cur) + (mt * 32 + l31) * LSTR + ks * 16 + h * 8];
                union { unsigned int d[4]; bf16x8 v; } u;
                u.d[0] = bfrag[ks][0]; u.d[1] = bfrag[ks][1];
                u.d[2] = bfrag[ks][2]; u.d[3] = bfrag[ks][3];
                oacc[mt] = __builtin_amdgcn_mfma_f32_32x32x16_bf16(vf, u.v, oacc[mt], 0, 0, 0);
            }
        }

        // ---- stage prefetched tile; one barrier per tile ----
        if (t + 1 < NT) {
            #pragma unroll
            for (int it = 0; it < 2; ++it) {
                int row = srow + it * 32;
                *(uint4*)&smem[KS_BASE(cur ^ 1)  + row * LSTR + sc8 * 8] = kreg[it];
                *(uint4*)&smem[VTS_BASE(cur ^ 1) + row * LSTR + sc8 * 8] = vreg[it];
            }
            __syncthreads();
        }
    }

    // ---- denominator: lane's dsum covers half the j's for i=l31; xor-32 completes ----
    float tot = dsum + __shfl_xor(dsum, 32);
    float inv = 1.0f / fmaxf(tot, 1e-4f);

    // ---- epilogue: normalize, transpose O^T -> O through LDS, coalesced store ----
    __syncthreads();   // all waves done reading Ks/Vts; safe to reuse smem
    float* ep = (float*)smem + (size_t)w * (32 * EPSTR);
    #pragma unroll
    for (int mt = 0; mt < 2; ++mt) {
        #pragma unroll
        for (int g = 0; g < 4; ++g) {
            f32x4 vv;
            vv[0] = oacc[mt][4*g+0] * inv;
            vv[1] = oacc[mt][4*g+1] * inv;
            vv[2] = oacc[mt][4*g+2] * inv;
            vv[3] = oacc[mt][4*g+3] * inv;
            // O[i=l31][d = mt*32 + 8g + 4h + 0..3]
            *(f32x4*)&ep[l31 * EPSTR + mt * 32 + 8 * g + 4 * h] = vv;
        }
    }
    // wave-private region: in-wave LDS ordering suffices (compiler emits lgkmcnt)
    const int quad4 = lane >> 4;
    const int c4    = lane & 15;
    #pragma unroll
    for (int rr = 0; rr < 8; ++rr) {
        int row = rr * 4 + quad4;
        f32x4 vv = *(const f32x4*)&ep[row * EPSTR + c4 * 4];
        *(f32x4*)&ob[(32 * w + row) * DH + c4 * 4] = vv;
    }
    #undef KS_BASE
    #undef VTS_BASE
}

// ---------------- fallback (self-contained, used if ws too small) ----------------
__global__ __launch_bounds__(256, 2)
void poly_attn_fallback(const float* __restrict__ qg, const float* __restrict__ kg,
                        const float* __restrict__ vg, float* __restrict__ og)
{
    __shared__ unsigned short Qs[64 * LSTR];
    __shared__ unsigned short Ksl[64 * LSTR];
    __shared__ unsigned short Vt[64 * LSTR];
    __shared__ unsigned short Xsl[64 * LSTR];

    const int tid  = threadIdx.x;
    const int lane = tid & 63;
    const int w    = tid >> 6;
    const int c    = lane & 15;
    const int quad = lane >> 4;
    const int i0   = w * 16;

    const int bh = blockIdx.y;
    const int q0 = blockIdx.x * 64;

    const float* qb = qg + ((size_t)bh * S_LEN + q0) * DH;
    const float* kb = kg + (size_t)bh * S_LEN * DH;
    const float* vb = vg + (size_t)bh * S_LEN * DH;
    float*       ob = og + ((size_t)bh * S_LEN + q0) * DH;

    {
        const float4* qf4 = (const float4*)qb;
        #pragma unroll
        for (int r = 0; r < 4; ++r) {
            int idx = r * 256 + tid;
            int row = idx >> 4, c4 = idx & 15;
            float4 f = qf4[idx];
            ushort4 hh;
            hh.x = f2bf(f.x); hh.y = f2bf(f.y); hh.z = f2bf(f.z); hh.w = f2bf(f.w);
            *(ushort4*)&Qs[row * LSTR + c4 * 4] = hh;
        }
    }

    f32x4 oacc[4];
    #pragma unroll
    for (int t = 0; t < 4; ++t) { oacc[t][0]=0.f; oacc[t][1]=0.f; oacc[t][2]=0.f; oacc[t][3]=0.f; }
    float dsum[4] = {0.f, 0.f, 0.f, 0.f};

    for (int t0 = 0; t0 < S_LEN; t0 += 64) {
        __syncthreads();
        {
            const float4* kf4 = (const float4*)(kb + (size_t)t0 * DH);
            const float4* vf4 = (const float4*)(vb + (size_t)t0 * DH);
            #pragma unroll
            for (int r = 0; r < 4; ++r) {
                int idx = r * 256 + tid;
                int row = idx >> 4, c4 = idx & 15;
                float4 f = kf4[idx];
                ushort4 hh;
                hh.x = f2bf(f.x); hh.y = f2bf(f.y); hh.z = f2bf(f.z); hh.w = f2bf(f.w);
                *(ushort4*)&Ksl[row * LSTR + c4 * 4] = hh;
                float4 g = vf4[idx];
                int d0 = c4 * 4;
                Vt[(d0 + 0) * LSTR + row] = f2bf(g.x);
                Vt[(d0 + 1) * LSTR + row] = f2bf(g.y);
                Vt[(d0 + 2) * LSTR + row] = f2bf(g.z);
                Vt[(d0 + 3) * LSTR + row] = f2bf(g.w);
            }
        }
        __syncthreads();

        f32x4 xacc[4];
        #pragma unroll
        for (int t = 0; t < 4; ++t) { xacc[t][0]=0.f; xacc[t][1]=0.f; xacc[t][2]=0.f; xacc[t][3]=0.f; }
        #pragma unroll
        for (int k0 = 0; k0 < 64; k0 += 32) {
            bf16x8 af = *(const bf16x8*)&Qs[(i0 + c) * LSTR + k0 + quad * 8];
            #pragma unroll
            for (int tn = 0; tn < 4; ++tn) {
                bf16x8 bfg = *(const bf16x8*)&Ksl[(tn * 16 + c) * LSTR + k0 + quad * 8];
                xacc[tn] = __builtin_amdgcn_mfma_f32_16x16x32_bf16(af, bfg, xacc[tn], 0, 0, 0);
            }
        }
        #pragma unroll
        for (int tn = 0; tn < 4; ++tn)
            #pragma unroll
            for (int r = 0; r < 4; ++r) {
                float xv = xacc[tn][r];
                float xs = xv * xv;
                dsum[r] += xs;
                Xsl[(i0 + quad * 4 + r) * LSTR + tn * 16 + c] = f2bf(xs);
            }
        __syncthreads();

        #pragma unroll
        for (int k0 = 0; k0 < 64; k0 += 32) {
            bf16x8 af = *(const bf16x8*)&Xsl[(i0 + c) * LSTR + k0 + quad * 8];
            #pragma unroll
            for (int tn = 0; tn < 4; ++tn) {
                bf16x8 bfg = *(const bf16x8*)&Vt[(tn * 16 + c) * LSTR + k0 + quad * 8];
                oacc[tn] = __builtin_amdgcn_mfma_f32_16x16x32_bf16(af, bfg, oacc[tn], 0, 0, 0);
            }
        }
    }

    #pragma unroll
    for (int r = 0; r < 4; ++r) {
        float s = dsum[r];
        s += __shfl_xor(s, 1);
        s += __shfl_xor(s, 2);
        s += __shfl_xor(s, 4);
        s += __shfl_xor(s, 8);
        dsum[r] = 1.0f / fmaxf(s, 1e-4f);
    }
    #pragma unroll
    for (int tn = 0; tn < 4; ++tn)
        #pragma unroll
        for (int r = 0; r < 4; ++r)
            ob[(i0 + quad * 4 + r) * DH + tn * 16 + c] = oacc[tn][r] * dsum[r];
}

extern "C" void kernel_launch(void* const* d_in, const int* in_sizes, int n_in,
                              void* d_out, int out_size, void* d_ws, size_t ws_size,
                              hipStream_t stream) {
    (void)in_sizes; (void)n_in; (void)out_size;
    const float* q = (const float*)d_in[0];
    const float* k = (const float*)d_in[1];
    const float* v = (const float*)d_in[2];
    float* o = (float*)d_out;

    const size_t elems = (size_t)BH_N * PER_BH;              // 4,194,304
    const size_t need  = 2 * elems * sizeof(unsigned short); // 16.78 MB

    if (ws_size >= need) {
        unsigned short* kbf = (unsigned short*)d_ws;
        unsigned short* vtb = kbf + elems;
        prepass_kernel<<<dim3(S_LEN / 64, BH_N), 256, 0, stream>>>(k, v, kbf, vtb);
        poly_attn_main<<<dim3(S_LEN / BQ, BH_N), 256, 0, stream>>>(q, kbf, vtb, o);
    } else {
        poly_attn_fallback<<<dim3(S_LEN / 64, BH_N), 256, 0, stream>>>(q, k, v, o);
    }
}

// Round 5
// 155.481 us; speedup vs baseline: 1.0238x; 1.0238x over previous
//
#include <hip/hip_runtime.h>

// PolynomialAttn: B=2,H=16,S=2048,D=64, degree=2, eps=1e-4, fp32 in/out.
// v5: v4 dataflow (32x32x16 MFMA, X^T=K*Q^T, in-register permlane C->B
// transform, double-buffered K/V LDS) but BQ=64 with wave-pairs splitting the
// j-range of each KV tile => 1024 blocks => 4 blocks/CU (was 2). Partials
// combine through LDS once at the end. Occupancy doubles to hide the MFMA
// dependency chains that made v4 latency-bound.

#define S_LEN 2048
#define DH    64
#define BQ    64
#define BK    64
#define LSTR  72        // LDS row stride in ushorts (pad 8: 16B-aligned)
#define EPSTR 68        // epilogue fp32 stride
#define PSTR  65        // prepass transpose LDS stride
#define BH_N  32        // B*H
#define PER_BH (S_LEN * DH)   // 131072 elems
#define NT    (S_LEN / BK)    // 32 KV tiles

typedef __bf16 bf16x8 __attribute__((ext_vector_type(8)));
typedef __bf16 bf16x2 __attribute__((ext_vector_type(2)));
typedef float  f32x4  __attribute__((ext_vector_type(4)));
typedef float  f32x16 __attribute__((ext_vector_type(16)));
typedef unsigned int uivec2 __attribute__((ext_vector_type(2)));

__device__ __forceinline__ unsigned short f2bf(float f) {
    union { float f; unsigned int u; } x; x.f = f;
    unsigned int u = x.u;
    return (unsigned short)((u + 0x7fffu + ((u >> 16) & 1u)) >> 16);  // RNE
}

__device__ __forceinline__ unsigned int pack2bf(float lo, float hi) {
#if __has_builtin(__builtin_amdgcn_cvt_pk_bf16_f32)
    bf16x2 p = __builtin_amdgcn_cvt_pk_bf16_f32(lo, hi);
    union { bf16x2 v; unsigned int u; } c; c.v = p;
    return c.u;
#else
    return (unsigned int)f2bf(lo) | ((unsigned int)f2bf(hi) << 16);
#endif
}

__device__ __forceinline__ void pl32swap(unsigned int& a, unsigned int& b) {
#if __has_builtin(__builtin_amdgcn_permlane32_swap)
    uivec2 r = __builtin_amdgcn_permlane32_swap(a, b, false, false);
    a = r[0]; b = r[1];
#else
    asm("v_permlane32_swap_b32 %0, %1" : "+v"(a), "+v"(b));
#endif
}

// ---------------- fused prepass: K fp32->bf16 copy + V fp32 -> V^T bf16 ----------------
__global__ __launch_bounds__(256)
void prepass_kernel(const float* __restrict__ kg, const float* __restrict__ vg,
                    unsigned short* __restrict__ kbf, unsigned short* __restrict__ vt)
{
    __shared__ unsigned short Ls[64 * PSTR];
    const int tid = threadIdx.x;
    const int bh  = blockIdx.y;
    const int t0  = blockIdx.x * 64;
    const size_t base = (size_t)bh * PER_BH + (size_t)t0 * DH;

    {
        const float4* src = (const float4*)(kg + base + (size_t)tid * 16);
        float4 a = src[0], b = src[1], c = src[2], d = src[3];
        union { unsigned short h[8]; uint4 v; } u0, u1;
        u0.h[0]=f2bf(a.x); u0.h[1]=f2bf(a.y); u0.h[2]=f2bf(a.z); u0.h[3]=f2bf(a.w);
        u0.h[4]=f2bf(b.x); u0.h[5]=f2bf(b.y); u0.h[6]=f2bf(b.z); u0.h[7]=f2bf(b.w);
        u1.h[0]=f2bf(c.x); u1.h[1]=f2bf(c.y); u1.h[2]=f2bf(c.z); u1.h[3]=f2bf(c.w);
        u1.h[4]=f2bf(d.x); u1.h[5]=f2bf(d.y); u1.h[6]=f2bf(d.z); u1.h[7]=f2bf(d.w);
        uint4* dst = (uint4*)(kbf + base + (size_t)tid * 16);
        dst[0] = u0.v; dst[1] = u1.v;
    }

    const float* vb = vg + base;
    #pragma unroll
    for (int r = 0; r < 4; ++r) {
        int idx = r * 256 + tid;
        int row = idx >> 4, c4 = idx & 15;
        float4 f = ((const float4*)vb)[idx];
        unsigned short* p = &Ls[row * PSTR + c4 * 4];
        p[0] = f2bf(f.x); p[1] = f2bf(f.y); p[2] = f2bf(f.z); p[3] = f2bf(f.w);
    }
    __syncthreads();
    #pragma unroll
    for (int r = 0; r < 2; ++r) {
        int idx = r * 256 + tid;
        int d = idx >> 3, j8 = idx & 7;
        union { unsigned short h[8]; uint4 v; } u;
        #pragma unroll
        for (int jj = 0; jj < 8; ++jj) u.h[jj] = Ls[(j8 * 8 + jj) * PSTR + d];
        *(uint4*)(vt + (size_t)bh * PER_BH + (size_t)d * S_LEN + t0 + j8 * 8) = u.v;
    }
}

// ---------------- main kernel ----------------
__global__ __launch_bounds__(256, 4)
void poly_attn_main(const float* __restrict__ qg,
                    const unsigned short* __restrict__ kbf,
                    const unsigned short* __restrict__ vtbf,
                    float* __restrict__ og)
{
    // [Ks buf0 | Ks buf1 | Vts buf0 | Vts buf1]; reused as 4 per-wave fp32
    // combine buffers (32 x EPSTR each) in the epilogue.
    __shared__ __align__(16) unsigned short smem[4 * 64 * LSTR];
    __shared__ float dbuf[128];   // per-wave column denominator partials
    #define KS_BASE(b)  ((b) * 64 * LSTR)
    #define VTS_BASE(b) ((2 + (b)) * 64 * LSTR)

    const int tid  = threadIdx.x;
    const int lane = tid & 63;
    const int w    = tid >> 6;
    const int p    = w >> 1;      // pair id: Q rows [32p, 32p+32)
    const int e    = w & 1;       // j-half of each KV tile: [32e, 32e+32)
    const int l31  = lane & 31;
    const int h    = lane >> 5;

    const int bh = blockIdx.y;
    const int q0 = blockIdx.x * BQ;

    const float* qb = qg + ((size_t)bh * S_LEN + q0) * DH;
    const unsigned short* kb  = kbf  + (size_t)bh * PER_BH;
    const unsigned short* vtb = vtbf + (size_t)bh * PER_BH;
    float* ob = og + ((size_t)bh * S_LEN + q0) * DH;

    // ---- preload Q B-fragments: lane holds Q[32p+l31][16ks + 8h + 0..7] ----
    bf16x8 qfrag[4];
    #pragma unroll
    for (int ks = 0; ks < 4; ++ks) {
        const float* qp = qb + (32 * p + l31) * DH + ks * 16 + h * 8;
        float4 f0 = *(const float4*)qp;
        float4 f1 = *(const float4*)(qp + 4);
        union { unsigned int d[4]; bf16x8 v; } u;
        u.d[0] = pack2bf(f0.x, f0.y);
        u.d[1] = pack2bf(f0.z, f0.w);
        u.d[2] = pack2bf(f1.x, f1.y);
        u.d[3] = pack2bf(f1.z, f1.w);
        qfrag[ks] = u.v;
    }

    f32x16 oacc[2];   // partial O^T[d = mt*32 + (r&3)+8*(r>>2)+4h][i = l31]
    #pragma unroll
    for (int mt = 0; mt < 2; ++mt)
        #pragma unroll
        for (int r = 0; r < 16; ++r) oacc[mt][r] = 0.f;
    float dsum = 0.f;

    // staging: 256 threads move 64x64 bf16 K + 64x64 V^T per tile
    const int srow = tid >> 3;
    const int sc8  = tid & 7;

    uint4 kreg[2], vreg[2];
    #pragma unroll
    for (int it = 0; it < 2; ++it) {
        int row = srow + it * 32;
        kreg[it] = *(const uint4*)(kb + (size_t)row * DH + sc8 * 8);
        vreg[it] = *(const uint4*)(vtb + (size_t)row * S_LEN + sc8 * 8);
    }
    #pragma unroll
    for (int it = 0; it < 2; ++it) {
        int row = srow + it * 32;
        *(uint4*)&smem[KS_BASE(0)  + row * LSTR + sc8 * 8] = kreg[it];
        *(uint4*)&smem[VTS_BASE(0) + row * LSTR + sc8 * 8] = vreg[it];
    }
    __syncthreads();

    for (int t = 0; t < NT; ++t) {
        const int cur = t & 1;
        if (t + 1 < NT) {
            const int t0n = (t + 1) * BK;
            #pragma unroll
            for (int it = 0; it < 2; ++it) {
                int row = srow + it * 32;
                kreg[it] = *(const uint4*)(kb + (size_t)(t0n + row) * DH + sc8 * 8);
                vreg[it] = *(const uint4*)(vtb + (size_t)row * S_LEN + t0n + sc8 * 8);
            }
        }

        // ---- X^T = K Q^T for this wave's j-half (4 MFMAs) ----
        f32x16 acc;
        #pragma unroll
        for (int r = 0; r < 16; ++r) acc[r] = 0.f;
        #pragma unroll
        for (int ks = 0; ks < 4; ++ks) {
            bf16x8 kf = *(const bf16x8*)&smem[KS_BASE(cur) + (e * 32 + l31) * LSTR + ks * 16 + h * 8];
            acc = __builtin_amdgcn_mfma_f32_32x32x16_bf16(kf, qfrag[ks], acc, 0, 0, 0);
        }

        // ---- square, denom, pack; permlane C->B transform (in-register) ----
        unsigned int pk[4][2];
        #pragma unroll
        for (int g = 0; g < 4; ++g) {
            float x0 = acc[4*g+0], x1 = acc[4*g+1], x2 = acc[4*g+2], x3 = acc[4*g+3];
            x0 *= x0; x1 *= x1; x2 *= x2; x3 *= x3;
            dsum += (x0 + x1) + (x2 + x3);
            pk[g][0] = pack2bf(x0, x1);
            pk[g][1] = pack2bf(x2, x3);
        }
        unsigned int bfrag[2][4];   // B: X^2[j = 32e + 16ksl + 8h + b][i = l31]
        #pragma unroll
        for (int ksl = 0; ksl < 2; ++ksl) {
            unsigned int a0 = pk[2*ksl][0], b0 = pk[2*ksl+1][0];
            unsigned int a1 = pk[2*ksl][1], b1 = pk[2*ksl+1][1];
            pl32swap(a0, b0);
            pl32swap(a1, b1);
            bfrag[ksl][0] = a0; bfrag[ksl][1] = a1;
            bfrag[ksl][2] = b0; bfrag[ksl][3] = b1;
        }

        // ---- O^T += V^T X^2T over this wave's j-half (4 MFMAs) ----
        #pragma unroll
        for (int mt = 0; mt < 2; ++mt) {
            #pragma unroll
            for (int ksl = 0; ksl < 2; ++ksl) {
                bf16x8 vf = *(const bf16x8*)&smem[VTS_BASE(cur) + (mt * 32 + l31) * LSTR + e * 32 + ksl * 16 + h * 8];
                union { unsigned int d[4]; bf16x8 v; } u;
                u.d[0] = bfrag[ksl][0]; u.d[1] = bfrag[ksl][1];
                u.d[2] = bfrag[ksl][2]; u.d[3] = bfrag[ksl][3];
                oacc[mt] = __builtin_amdgcn_mfma_f32_32x32x16_bf16(vf, u.v, oacc[mt], 0, 0, 0);
            }
        }

        if (t + 1 < NT) {
            #pragma unroll
            for (int it = 0; it < 2; ++it) {
                int row = srow + it * 32;
                *(uint4*)&smem[KS_BASE(cur ^ 1)  + row * LSTR + sc8 * 8] = kreg[it];
                *(uint4*)&smem[VTS_BASE(cur ^ 1) + row * LSTR + sc8 * 8] = vreg[it];
            }
            __syncthreads();
        }
    }

    // ---- per-wave partial denominator for column i = l31 over its j-half ----
    float wavetot = dsum + __shfl_xor(dsum, 32);

    // ---- epilogue: write partials to LDS, combine wave pairs, store ----
    __syncthreads();   // everyone done with K/V buffers
    float* ep = (float*)smem + (size_t)w * (32 * EPSTR);
    #pragma unroll
    for (int mt = 0; mt < 2; ++mt) {
        #pragma unroll
        for (int g = 0; g < 4; ++g) {
            f32x4 vv;
            vv[0] = oacc[mt][4*g+0];
            vv[1] = oacc[mt][4*g+1];
            vv[2] = oacc[mt][4*g+2];
            vv[3] = oacc[mt][4*g+3];
            // O[i=l31][d = mt*32 + 8g + 4h + 0..3]
            *(f32x4*)&ep[l31 * EPSTR + mt * 32 + 8 * g + 4 * h] = vv;
        }
    }
    if (h == 0) dbuf[w * 32 + l31] = wavetot;
    __syncthreads();

    // pair p combine: wave e handles local rows [16e, 16e+16)
    const float* ep0 = (float*)smem + (size_t)(2 * p)     * (32 * EPSTR);
    const float* ep1 = (float*)smem + (size_t)(2 * p + 1) * (32 * EPSTR);
    const int lrow = e * 16 + (lane >> 2);
    const float den = dbuf[2 * p * 32 + lrow] + dbuf[(2 * p + 1) * 32 + lrow];
    const float inv = 1.0f / fmaxf(den, 1e-4f);
    #pragma unroll
    for (int it = 0; it < 4; ++it) {
        int d0 = (lane & 3) * 16 + it * 4;
        f32x4 a = *(const f32x4*)&ep0[lrow * EPSTR + d0];
        f32x4 b = *(const f32x4*)&ep1[lrow * EPSTR + d0];
        f32x4 s;
        s[0] = (a[0] + b[0]) * inv;
        s[1] = (a[1] + b[1]) * inv;
        s[2] = (a[2] + b[2]) * inv;
        s[3] = (a[3] + b[3]) * inv;
        *(f32x4*)&ob[(32 * p + lrow) * DH + d0] = s;
    }
    #undef KS_BASE
    #undef VTS_BASE
}

// ---------------- fallback (self-contained, used if ws too small) ----------------
__global__ __launch_bounds__(256, 2)
void poly_attn_fallback(const float* __restrict__ qg, const float* __restrict__ kg,
                        const float* __restrict__ vg, float* __restrict__ og)
{
    __shared__ unsigned short Qs[64 * LSTR];
    __shared__ unsigned short Ksl[64 * LSTR];
    __shared__ unsigned short Vt[64 * LSTR];
    __shared__ unsigned short Xsl[64 * LSTR];

    const int tid  = threadIdx.x;
    const int lane = tid & 63;
    const int w    = tid >> 6;
    const int c    = lane & 15;
    const int quad = lane >> 4;
    const int i0   = w * 16;

    const int bh = blockIdx.y;
    const int q0 = blockIdx.x * 64;

    const float* qb = qg + ((size_t)bh * S_LEN + q0) * DH;
    const float* kb = kg + (size_t)bh * S_LEN * DH;
    const float* vb = vg + (size_t)bh * S_LEN * DH;
    float*       ob = og + ((size_t)bh * S_LEN + q0) * DH;

    {
        const float4* qf4 = (const float4*)qb;
        #pragma unroll
        for (int r = 0; r < 4; ++r) {
            int idx = r * 256 + tid;
            int row = idx >> 4, c4 = idx & 15;
            float4 f = qf4[idx];
            ushort4 hh;
            hh.x = f2bf(f.x); hh.y = f2bf(f.y); hh.z = f2bf(f.z); hh.w = f2bf(f.w);
            *(ushort4*)&Qs[row * LSTR + c4 * 4] = hh;
        }
    }

    f32x4 oacc[4];
    #pragma unroll
    for (int t = 0; t < 4; ++t) { oacc[t][0]=0.f; oacc[t][1]=0.f; oacc[t][2]=0.f; oacc[t][3]=0.f; }
    float dsum[4] = {0.f, 0.f, 0.f, 0.f};

    for (int t0 = 0; t0 < S_LEN; t0 += 64) {
        __syncthreads();
        {
            const float4* kf4 = (const float4*)(kb + (size_t)t0 * DH);
            const float4* vf4 = (const float4*)(vb + (size_t)t0 * DH);
            #pragma unroll
            for (int r = 0; r < 4; ++r) {
                int idx = r * 256 + tid;
                int row = idx >> 4, c4 = idx & 15;
                float4 f = kf4[idx];
                ushort4 hh;
                hh.x = f2bf(f.x); hh.y = f2bf(f.y); hh.z = f2bf(f.z); hh.w = f2bf(f.w);
                *(ushort4*)&Ksl[row * LSTR + c4 * 4] = hh;
                float4 g = vf4[idx];
                int d0 = c4 * 4;
                Vt[(d0 + 0) * LSTR + row] = f2bf(g.x);
                Vt[(d0 + 1) * LSTR + row] = f2bf(g.y);
                Vt[(d0 + 2) * LSTR + row] = f2bf(g.z);
                Vt[(d0 + 3) * LSTR + row] = f2bf(g.w);
            }
        }
        __syncthreads();

        f32x4 xacc[4];
        #pragma unroll
        for (int t = 0; t < 4; ++t) { xacc[t][0]=0.f; xacc[t][1]=0.f; xacc[t][2]=0.f; xacc[t][3]=0.f; }
        #pragma unroll
        for (int k0 = 0; k0 < 64; k0 += 32) {
            bf16x8 af = *(const bf16x8*)&Qs[(i0 + c) * LSTR + k0 + quad * 8];
            #pragma unroll
            for (int tn = 0; tn < 4; ++tn) {
                bf16x8 bfg = *(const bf16x8*)&Ksl[(tn * 16 + c) * LSTR + k0 + quad * 8];
                xacc[tn] = __builtin_amdgcn_mfma_f32_16x16x32_bf16(af, bfg, xacc[tn], 0, 0, 0);
            }
        }
        #pragma unroll
        for (int tn = 0; tn < 4; ++tn)
            #pragma unroll
            for (int r = 0; r < 4; ++r) {
                float xv = xacc[tn][r];
                float xs = xv * xv;
                dsum[r] += xs;
                Xsl[(i0 + quad * 4 + r) * LSTR + tn * 16 + c] = f2bf(xs);
            }
        __syncthreads();

        #pragma unroll
        for (int k0 = 0; k0 < 64; k0 += 32) {
            bf16x8 af = *(const bf16x8*)&Xsl[(i0 + c) * LSTR + k0 + quad * 8];
            #pragma unroll
            for (int tn = 0; tn < 4; ++tn) {
                bf16x8 bfg = *(const bf16x8*)&Vt[(tn * 16 + c) * LSTR + k0 + quad * 8];
                oacc[tn] = __builtin_amdgcn_mfma_f32_16x16x32_bf16(af, bfg, oacc[tn], 0, 0, 0);
            }
        }
    }

    #pragma unroll
    for (int r = 0; r < 4; ++r) {
        float s = dsum[r];
        s += __shfl_xor(s, 1);
        s += __shfl_xor(s, 2);
        s += __shfl_xor(s, 4);
        s += __shfl_xor(s, 8);
        dsum[r] = 1.0f / fmaxf(s, 1e-4f);
    }
    #pragma unroll
    for (int tn = 0; tn < 4; ++tn)
        #pragma unroll
        for (int r = 0; r < 4; ++r)
            ob[(i0 + quad * 4 + r) * DH + tn * 16 + c] = oacc[tn][r] * dsum[r];
}

extern "C" void kernel_launch(void* const* d_in, const int* in_sizes, int n_in,
                              void* d_out, int out_size, void* d_ws, size_t ws_size,
                              hipStream_t stream) {
    (void)in_sizes; (void)n_in; (void)out_size;
    const float* q = (const float*)d_in[0];
    const float* k = (const float*)d_in[1];
    const float* v = (const float*)d_in[2];
    float* o = (float*)d_out;

    const size_t elems = (size_t)BH_N * PER_BH;              // 4,194,304
    const size_t need  = 2 * elems * sizeof(unsigned short); // 16.78 MB

    if (ws_size >= need) {
        unsigned short* kbf = (unsigned short*)d_ws;
        unsigned short* vtb = kbf + elems;
        prepass_kernel<<<dim3(S_LEN / 64, BH_N), 256, 0, stream>>>(k, v, kbf, vtb);
        poly_attn_main<<<dim3(S_LEN / BQ, BH_N), 256, 0, stream>>>(q, kbf, vtb, o);
    } else {
        poly_attn_fallback<<<dim3(S_LEN / 64, BH_N), 256, 0, stream>>>(q, k, v, o);
    }
}

// Round 6
// 145.773 us; speedup vs baseline: 1.0919x; 1.0666x over previous
//
#include <hip/hip_runtime.h>

// PolynomialAttn: B=2,H=16,S=2048,D=64, degree=2, eps=1e-4, fp32 in/out.
// v6: barrier-free, LDS-free main loop. Prepass writes K and V^T into
// MFMA-FRAGMENT-ORDER streams in d_ws (1KB blocks, lane-linear), so the main
// kernel streams 8KB/wave/tile of perfectly-coalesced global loads straight
// into MFMA operand registers (software-pipelined, fine-grained vmcnt, no
// syncthreads, no LDS in the loop). XCD swizzle keeps each bh's stream in one
// XCD's L2. Epilogue pair-combine through small LDS as in v5.

#define S_LEN 2048
#define DH    64
#define BQ    64
#define BK    64
#define EPSTR 68        // epilogue fp32 stride
#define PSTR  65        // prepass V-transpose LDS stride
#define BH_N  32        // B*H
#define PER_BH (S_LEN * DH)   // 131072 elems
#define NT    (S_LEN / BK)    // 32 KV tiles

typedef __bf16 bf16x8 __attribute__((ext_vector_type(8)));
typedef __bf16 bf16x2 __attribute__((ext_vector_type(2)));
typedef float  f32x4  __attribute__((ext_vector_type(4)));
typedef float  f32x16 __attribute__((ext_vector_type(16)));
typedef unsigned int uivec2 __attribute__((ext_vector_type(2)));

__device__ __forceinline__ unsigned short f2bf(float f) {
    union { float f; unsigned int u; } x; x.f = f;
    unsigned int u = x.u;
    return (unsigned short)((u + 0x7fffu + ((u >> 16) & 1u)) >> 16);  // RNE
}

__device__ __forceinline__ unsigned int pack2bf(float lo, float hi) {
#if __has_builtin(__builtin_amdgcn_cvt_pk_bf16_f32)
    bf16x2 p = __builtin_amdgcn_cvt_pk_bf16_f32(lo, hi);
    union { bf16x2 v; unsigned int u; } c; c.v = p;
    return c.u;
#else
    return (unsigned int)f2bf(lo) | ((unsigned int)f2bf(hi) << 16);
#endif
}

__device__ __forceinline__ void pl32swap(unsigned int& a, unsigned int& b) {
#if __has_builtin(__builtin_amdgcn_permlane32_swap)
    uivec2 r = __builtin_amdgcn_permlane32_swap(a, b, false, false);
    a = r[0]; b = r[1];
#else
    asm("v_permlane32_swap_b32 %0, %1" : "+v"(a), "+v"(b));
#endif
}

// ---------------- prepass: K -> fragment-order bf16, V -> V^T fragment-order bf16 ----
// Kf layout (ushorts): [bh][t][e][ks][lane]*8 ; lane(l31,h) holds
//   K[bh][64t + 32e + l31][16ks + 8h + 0..7]
// Vf layout (ushorts): [bh][t][e][ksl][mt][lane]*8 ; lane(l31,h) holds
//   V^T[bh][mt*32 + l31][64t + 32e + 16ksl + 8h + 0..7]
__global__ __launch_bounds__(256)
void prepass_kernel(const float* __restrict__ kg, const float* __restrict__ vg,
                    unsigned short* __restrict__ kfo, unsigned short* __restrict__ vfo)
{
    __shared__ unsigned short Lk[64 * 72];
    __shared__ unsigned short Lv[64 * PSTR];
    const int tid = threadIdx.x;
    const int bh  = blockIdx.y;
    const int t   = blockIdx.x;
    const size_t base = (size_t)bh * PER_BH + (size_t)t * 64 * DH;

    const float4* kf4 = (const float4*)(kg + base);
    const float4* vf4 = (const float4*)(vg + base);
    #pragma unroll
    for (int r = 0; r < 4; ++r) {
        int idx = r * 256 + tid;              // float4 index in 64x64 tile
        int row = idx >> 4, c4 = idx & 15;
        float4 f = kf4[idx];
        ushort4 hh;
        hh.x = f2bf(f.x); hh.y = f2bf(f.y); hh.z = f2bf(f.z); hh.w = f2bf(f.w);
        *(ushort4*)&Lk[row * 72 + c4 * 4] = hh;
        float4 g = vf4[idx];
        unsigned short* pv = &Lv[row * PSTR + c4 * 4];
        pv[0] = f2bf(g.x); pv[1] = f2bf(g.y); pv[2] = f2bf(g.z); pv[3] = f2bf(g.w);
    }
    __syncthreads();

    // K fragments: 512 16B chunks, pos = ((e*4+ks)*64 + lane)
    unsigned short* kout = kfo + (size_t)bh * PER_BH + (size_t)t * 4096;
    #pragma unroll
    for (int r = 0; r < 2; ++r) {
        int pos = r * 256 + tid;
        int lam = pos & 63, rest = pos >> 6;
        int e = rest >> 2, ks = rest & 3;
        int l31 = lam & 31, h = lam >> 5;
        uint4 v = *(const uint4*)&Lk[(e * 32 + l31) * 72 + ks * 16 + h * 8];
        *(uint4*)(kout + (size_t)pos * 8) = v;
    }
    // V fragments: 512 16B chunks, pos = (((e*2+ksl)*2+mt)*64 + lane)
    unsigned short* vout = vfo + (size_t)bh * PER_BH + (size_t)t * 4096;
    #pragma unroll
    for (int r = 0; r < 2; ++r) {
        int pos = r * 256 + tid;
        int lam = pos & 63, rest = pos >> 6;
        int e = rest >> 2, ksl = (rest >> 1) & 1, mt = rest & 1;
        int l31 = lam & 31, h = lam >> 5;
        int d  = mt * 32 + l31;
        int j0 = e * 32 + ksl * 16 + h * 8;
        union { unsigned short s[8]; uint4 u; } u;
        #pragma unroll
        for (int jj = 0; jj < 8; ++jj) u.s[jj] = Lv[(j0 + jj) * PSTR + d];
        *(uint4*)(vout + (size_t)pos * 8) = u.u;
    }
}

// ---------------- main kernel: no LDS, no barriers in the K-loop ----------------
__global__ __launch_bounds__(256, 4)
void poly_attn_main(const float* __restrict__ qg,
                    const unsigned short* __restrict__ kfo,
                    const unsigned short* __restrict__ vfo,
                    float* __restrict__ og)
{
    __shared__ float epb[4 * 32 * EPSTR];   // epilogue O^T partials
    __shared__ float dbuf[128];             // per-wave denominator partials

    const int tid  = threadIdx.x;
    const int lane = tid & 63;
    const int w    = tid >> 6;
    const int p    = w >> 1;      // pair id: Q rows [32p, 32p+32)
    const int e    = w & 1;       // j-half of each KV tile
    const int l31  = lane & 31;
    const int h    = lane >> 5;

    // XCD swizzle: id%8 selects XCD; give each XCD 4 bh's (2MB K+V working set in its L2)
    const int id = blockIdx.x;
    const int bh = (id & 7) * 4 + ((id >> 3) & 3);
    const int qt = id >> 5;
    const int q0 = qt * BQ;

    const float* qb = qg + ((size_t)bh * S_LEN + q0) * DH;
    const unsigned short* kw = kfo + (size_t)bh * PER_BH + e * 2048 + (size_t)lane * 8;
    const unsigned short* vw = vfo + (size_t)bh * PER_BH + e * 2048 + (size_t)lane * 8;
    float* ob = og + ((size_t)bh * S_LEN + q0) * DH;

    // ---- Q B-fragments: lane holds Q[q0 + 32p + l31][16ks + 8h + 0..7] ----
    bf16x8 qfrag[4];
    #pragma unroll
    for (int ks = 0; ks < 4; ++ks) {
        const float* qp = qb + (32 * p + l31) * DH + ks * 16 + h * 8;
        float4 f0 = *(const float4*)qp;
        float4 f1 = *(const float4*)(qp + 4);
        union { unsigned int d[4]; bf16x8 v; } u;
        u.d[0] = pack2bf(f0.x, f0.y);
        u.d[1] = pack2bf(f0.z, f0.w);
        u.d[2] = pack2bf(f1.x, f1.y);
        u.d[3] = pack2bf(f1.z, f1.w);
        qfrag[ks] = u.v;
    }

    f32x16 oacc[2];   // O^T[d = mt*32 + (r&3)+8*(r>>2)+4h][i = l31] partial over j-half
    #pragma unroll
    for (int mt = 0; mt < 2; ++mt)
        #pragma unroll
        for (int r = 0; r < 16; ++r) oacc[mt][r] = 0.f;
    float dsum = 0.f;

    uint4 kbuf[2][4], vbuf[4];
    #pragma unroll
    for (int ks = 0; ks < 4; ++ks)
        kbuf[0][ks] = *(const uint4*)(kw + ks * 512);

    // Per tile: issue V(t) loads -> QK MFMAs -> issue K(t+1) loads -> transform
    // -> PV MFMAs. Loads stay in flight across tiles (vmcnt(N), no barrier).
#define TILE_BODY(T, KCUR, KNXT)                                                    \
    {                                                                               \
        const unsigned short* vt_ = vw + (size_t)(T) * 4096;                        \
        _Pragma("unroll")                                                           \
        for (int x = 0; x < 4; ++x)                                                 \
            vbuf[x] = *(const uint4*)(vt_ + x * 512);                               \
        f32x16 acc;                                                                 \
        _Pragma("unroll")                                                           \
        for (int r = 0; r < 16; ++r) acc[r] = 0.f;                                  \
        _Pragma("unroll")                                                           \
        for (int ks = 0; ks < 4; ++ks) {                                            \
            union { uint4 u; bf16x8 v; } kc; kc.u = KCUR[ks];                       \
            acc = __builtin_amdgcn_mfma_f32_32x32x16_bf16(kc.v, qfrag[ks], acc, 0, 0, 0); \
        }                                                                           \
        const unsigned short* kn_ = kw + (size_t)((T) + 1) * 4096;                  \
        _Pragma("unroll")                                                           \
        for (int ks = 0; ks < 4; ++ks)                                              \
            KNXT[ks] = *(const uint4*)(kn_ + ks * 512);                             \
        unsigned int pk[4][2];                                                      \
        _Pragma("unroll")                                                           \
        for (int g = 0; g < 4; ++g) {                                               \
            float x0 = acc[4*g+0], x1 = acc[4*g+1], x2 = acc[4*g+2], x3 = acc[4*g+3]; \
            x0 *= x0; x1 *= x1; x2 *= x2; x3 *= x3;                                 \
            dsum += (x0 + x1) + (x2 + x3);                                          \
            pk[g][0] = pack2bf(x0, x1);                                             \
            pk[g][1] = pack2bf(x2, x3);                                             \
        }                                                                           \
        _Pragma("unroll")                                                           \
        for (int ksl = 0; ksl < 2; ++ksl) {                                         \
            unsigned int a0 = pk[2*ksl][0], b0 = pk[2*ksl+1][0];                    \
            unsigned int a1 = pk[2*ksl][1], b1 = pk[2*ksl+1][1];                    \
            pl32swap(a0, b0);                                                       \
            pl32swap(a1, b1);                                                       \
            union { unsigned int d[4]; bf16x8 v; } bu;                              \
            bu.d[0] = a0; bu.d[1] = a1; bu.d[2] = b0; bu.d[3] = b1;                 \
            _Pragma("unroll")                                                       \
            for (int mt = 0; mt < 2; ++mt) {                                        \
                union { uint4 u; bf16x8 v; } vv; vv.u = vbuf[ksl * 2 + mt];         \
                oacc[mt] = __builtin_amdgcn_mfma_f32_32x32x16_bf16(vv.v, bu.v, oacc[mt], 0, 0, 0); \
            }                                                                       \
        }                                                                           \
    }

    for (int tp = 0; tp < NT; tp += 2) {
        TILE_BODY(tp,     kbuf[0], kbuf[1]);
        TILE_BODY(tp + 1, kbuf[1], kbuf[0]);
        // note: last iteration's K(32) prefetch reads into the Vf region of
        // d_ws (in-bounds, never consumed) — branch-free tail.
    }
#undef TILE_BODY

    // ---- per-wave denominator partial for column i = l31 over its j-half ----
    float wavetot = dsum + __shfl_xor(dsum, 32);

    // ---- epilogue: write partials to LDS, combine wave pairs, store ----
    float* ep = epb + (size_t)w * (32 * EPSTR);
    #pragma unroll
    for (int mt = 0; mt < 2; ++mt) {
        #pragma unroll
        for (int g = 0; g < 4; ++g) {
            f32x4 vv;
            vv[0] = oacc[mt][4*g+0];
            vv[1] = oacc[mt][4*g+1];
            vv[2] = oacc[mt][4*g+2];
            vv[3] = oacc[mt][4*g+3];
            // O[i=l31][d = mt*32 + 8g + 4h + 0..3]
            *(f32x4*)&ep[l31 * EPSTR + mt * 32 + 8 * g + 4 * h] = vv;
        }
    }
    if (h == 0) dbuf[w * 32 + l31] = wavetot;
    __syncthreads();

    const float* ep0 = epb + (size_t)(2 * p)     * (32 * EPSTR);
    const float* ep1 = epb + (size_t)(2 * p + 1) * (32 * EPSTR);
    const int lrow = e * 16 + (lane >> 2);
    const float den = dbuf[2 * p * 32 + lrow] + dbuf[(2 * p + 1) * 32 + lrow];
    const float inv = 1.0f / fmaxf(den, 1e-4f);
    #pragma unroll
    for (int it = 0; it < 4; ++it) {
        int d0 = (lane & 3) * 16 + it * 4;
        f32x4 a = *(const f32x4*)&ep0[lrow * EPSTR + d0];
        f32x4 b = *(const f32x4*)&ep1[lrow * EPSTR + d0];
        f32x4 s;
        s[0] = (a[0] + b[0]) * inv;
        s[1] = (a[1] + b[1]) * inv;
        s[2] = (a[2] + b[2]) * inv;
        s[3] = (a[3] + b[3]) * inv;
        *(f32x4*)&ob[(32 * p + lrow) * DH + d0] = s;
    }
}

// ---------------- fallback (self-contained, used if ws too small) ----------------
#define LSTR 72
__global__ __launch_bounds__(256, 2)
void poly_attn_fallback(const float* __restrict__ qg, const float* __restrict__ kg,
                        const float* __restrict__ vg, float* __restrict__ og)
{
    __shared__ unsigned short Qs[64 * LSTR];
    __shared__ unsigned short Ksl[64 * LSTR];
    __shared__ unsigned short Vt[64 * LSTR];
    __shared__ unsigned short Xsl[64 * LSTR];

    const int tid  = threadIdx.x;
    const int lane = tid & 63;
    const int w    = tid >> 6;
    const int c    = lane & 15;
    const int quad = lane >> 4;
    const int i0   = w * 16;

    const int bh = blockIdx.y;
    const int q0 = blockIdx.x * 64;

    const float* qb = qg + ((size_t)bh * S_LEN + q0) * DH;
    const float* kb = kg + (size_t)bh * S_LEN * DH;
    const float* vb = vg + (size_t)bh * S_LEN * DH;
    float*       ob = og + ((size_t)bh * S_LEN + q0) * DH;

    {
        const float4* qf4 = (const float4*)qb;
        #pragma unroll
        for (int r = 0; r < 4; ++r) {
            int idx = r * 256 + tid;
            int row = idx >> 4, c4 = idx & 15;
            float4 f = qf4[idx];
            ushort4 hh;
            hh.x = f2bf(f.x); hh.y = f2bf(f.y); hh.z = f2bf(f.z); hh.w = f2bf(f.w);
            *(ushort4*)&Qs[row * LSTR + c4 * 4] = hh;
        }
    }

    f32x4 oacc[4];
    #pragma unroll
    for (int t = 0; t < 4; ++t) { oacc[t][0]=0.f; oacc[t][1]=0.f; oacc[t][2]=0.f; oacc[t][3]=0.f; }
    float dsum[4] = {0.f, 0.f, 0.f, 0.f};

    for (int t0 = 0; t0 < S_LEN; t0 += 64) {
        __syncthreads();
        {
            const float4* kf4 = (const float4*)(kb + (size_t)t0 * DH);
            const float4* vf4 = (const float4*)(vb + (size_t)t0 * DH);
            #pragma unroll
            for (int r = 0; r < 4; ++r) {
                int idx = r * 256 + tid;
                int row = idx >> 4, c4 = idx & 15;
                float4 f = kf4[idx];
                ushort4 hh;
                hh.x = f2bf(f.x); hh.y = f2bf(f.y); hh.z = f2bf(f.z); hh.w = f2bf(f.w);
                *(ushort4*)&Ksl[row * LSTR + c4 * 4] = hh;
                float4 g = vf4[idx];
                int d0 = c4 * 4;
                Vt[(d0 + 0) * LSTR + row] = f2bf(g.x);
                Vt[(d0 + 1) * LSTR + row] = f2bf(g.y);
                Vt[(d0 + 2) * LSTR + row] = f2bf(g.z);
                Vt[(d0 + 3) * LSTR + row] = f2bf(g.w);
            }
        }
        __syncthreads();

        f32x4 xacc[4];
        #pragma unroll
        for (int t = 0; t < 4; ++t) { xacc[t][0]=0.f; xacc[t][1]=0.f; xacc[t][2]=0.f; xacc[t][3]=0.f; }
        #pragma unroll
        for (int k0 = 0; k0 < 64; k0 += 32) {
            bf16x8 af = *(const bf16x8*)&Qs[(i0 + c) * LSTR + k0 + quad * 8];
            #pragma unroll
            for (int tn = 0; tn < 4; ++tn) {
                bf16x8 bfg = *(const bf16x8*)&Ksl[(tn * 16 + c) * LSTR + k0 + quad * 8];
                xacc[tn] = __builtin_amdgcn_mfma_f32_16x16x32_bf16(af, bfg, xacc[tn], 0, 0, 0);
            }
        }
        #pragma unroll
        for (int tn = 0; tn < 4; ++tn)
            #pragma unroll
            for (int r = 0; r < 4; ++r) {
                float xv = xacc[tn][r];
                float xs = xv * xv;
                dsum[r] += xs;
                Xsl[(i0 + quad * 4 + r) * LSTR + tn * 16 + c] = f2bf(xs);
            }
        __syncthreads();

        #pragma unroll
        for (int k0 = 0; k0 < 64; k0 += 32) {
            bf16x8 af = *(const bf16x8*)&Xsl[(i0 + c) * LSTR + k0 + quad * 8];
            #pragma unroll
            for (int tn = 0; tn < 4; ++tn) {
                bf16x8 bfg = *(const bf16x8*)&Vt[(tn * 16 + c) * LSTR + k0 + quad * 8];
                oacc[tn] = __builtin_amdgcn_mfma_f32_16x16x32_bf16(af, bfg, oacc[tn], 0, 0, 0);
            }
        }
    }

    #pragma unroll
    for (int r = 0; r < 4; ++r) {
        float s = dsum[r];
        s += __shfl_xor(s, 1);
        s += __shfl_xor(s, 2);
        s += __shfl_xor(s, 4);
        s += __shfl_xor(s, 8);
        dsum[r] = 1.0f / fmaxf(s, 1e-4f);
    }
    #pragma unroll
    for (int tn = 0; tn < 4; ++tn)
        #pragma unroll
        for (int r = 0; r < 4; ++r)
            ob[(i0 + quad * 4 + r) * DH + tn * 16 + c] = oacc[tn][r] * dsum[r];
}

extern "C" void kernel_launch(void* const* d_in, const int* in_sizes, int n_in,
                              void* d_out, int out_size, void* d_ws, size_t ws_size,
                              hipStream_t stream) {
    (void)in_sizes; (void)n_in; (void)out_size;
    const float* q = (const float*)d_in[0];
    const float* k = (const float*)d_in[1];
    const float* v = (const float*)d_in[2];
    float* o = (float*)d_out;

    const size_t elems = (size_t)BH_N * PER_BH;              // 4,194,304
    const size_t need  = 2 * elems * sizeof(unsigned short); // 16.78 MB

    if (ws_size >= need) {
        unsigned short* kfo = (unsigned short*)d_ws;
        unsigned short* vfo = kfo + elems;
        prepass_kernel<<<dim3(NT, BH_N), 256, 0, stream>>>(k, v, kfo, vfo);
        poly_attn_main<<<dim3(BH_N * S_LEN / BQ), 256, 0, stream>>>(q, kfo, vfo, o);
    } else {
        poly_attn_fallback<<<dim3(S_LEN / 64, BH_N), 256, 0, stream>>>(q, k, v, o);
    }
}

// Round 7
// 142.086 us; speedup vs baseline: 1.1203x; 1.0260x over previous
//
#include <hip/hip_runtime.h>

// PolynomialAttn: B=2,H=16,S=2048,D=64, degree=2, eps=1e-4, fp32 in/out.
// v7: v6 (barrier-free, LDS-free main loop on fragment-order K/V streams)
// + BOTH K and V register-prefetched one full tile ahead, all loads issued at
// tile top => every consumer waits on loads ~1 full tile (~400 cyc) old;
// steady-state vmcnt never drains. Tail via (t+1)&31 wrap (in-bounds).

#define S_LEN 2048
#define DH    64
#define BQ    64
#define BK    64
#define EPSTR 68        // epilogue fp32 stride
#define PSTR  65        // prepass V-transpose LDS stride
#define BH_N  32        // B*H
#define PER_BH (S_LEN * DH)   // 131072 elems
#define NT    (S_LEN / BK)    // 32 KV tiles

typedef __bf16 bf16x8 __attribute__((ext_vector_type(8)));
typedef __bf16 bf16x2 __attribute__((ext_vector_type(2)));
typedef float  f32x4  __attribute__((ext_vector_type(4)));
typedef float  f32x16 __attribute__((ext_vector_type(16)));
typedef unsigned int uivec2 __attribute__((ext_vector_type(2)));

__device__ __forceinline__ unsigned short f2bf(float f) {
    union { float f; unsigned int u; } x; x.f = f;
    unsigned int u = x.u;
    return (unsigned short)((u + 0x7fffu + ((u >> 16) & 1u)) >> 16);  // RNE
}

__device__ __forceinline__ unsigned int pack2bf(float lo, float hi) {
#if __has_builtin(__builtin_amdgcn_cvt_pk_bf16_f32)
    bf16x2 p = __builtin_amdgcn_cvt_pk_bf16_f32(lo, hi);
    union { bf16x2 v; unsigned int u; } c; c.v = p;
    return c.u;
#else
    return (unsigned int)f2bf(lo) | ((unsigned int)f2bf(hi) << 16);
#endif
}

__device__ __forceinline__ void pl32swap(unsigned int& a, unsigned int& b) {
#if __has_builtin(__builtin_amdgcn_permlane32_swap)
    uivec2 r = __builtin_amdgcn_permlane32_swap(a, b, false, false);
    a = r[0]; b = r[1];
#else
    asm("v_permlane32_swap_b32 %0, %1" : "+v"(a), "+v"(b));
#endif
}

// ---------------- prepass: K -> fragment-order bf16, V -> V^T fragment-order bf16 ----
// Kf layout (ushorts): [bh][t][e][ks][lane]*8 ; lane(l31,h) holds
//   K[bh][64t + 32e + l31][16ks + 8h + 0..7]
// Vf layout (ushorts): [bh][t][e][ksl][mt][lane]*8 ; lane(l31,h) holds
//   V^T[bh][mt*32 + l31][64t + 32e + 16ksl + 8h + 0..7]
__global__ __launch_bounds__(256)
void prepass_kernel(const float* __restrict__ kg, const float* __restrict__ vg,
                    unsigned short* __restrict__ kfo, unsigned short* __restrict__ vfo)
{
    __shared__ unsigned short Lk[64 * 72];
    __shared__ unsigned short Lv[64 * PSTR];
    const int tid = threadIdx.x;
    const int bh  = blockIdx.y;
    const int t   = blockIdx.x;
    const size_t base = (size_t)bh * PER_BH + (size_t)t * 64 * DH;

    const float4* kf4 = (const float4*)(kg + base);
    const float4* vf4 = (const float4*)(vg + base);
    #pragma unroll
    for (int r = 0; r < 4; ++r) {
        int idx = r * 256 + tid;              // float4 index in 64x64 tile
        int row = idx >> 4, c4 = idx & 15;
        float4 f = kf4[idx];
        ushort4 hh;
        hh.x = f2bf(f.x); hh.y = f2bf(f.y); hh.z = f2bf(f.z); hh.w = f2bf(f.w);
        *(ushort4*)&Lk[row * 72 + c4 * 4] = hh;
        float4 g = vf4[idx];
        unsigned short* pv = &Lv[row * PSTR + c4 * 4];
        pv[0] = f2bf(g.x); pv[1] = f2bf(g.y); pv[2] = f2bf(g.z); pv[3] = f2bf(g.w);
    }
    __syncthreads();

    // K fragments: 512 16B chunks, pos = ((e*4+ks)*64 + lane)
    unsigned short* kout = kfo + (size_t)bh * PER_BH + (size_t)t * 4096;
    #pragma unroll
    for (int r = 0; r < 2; ++r) {
        int pos = r * 256 + tid;
        int lam = pos & 63, rest = pos >> 6;
        int e = rest >> 2, ks = rest & 3;
        int l31 = lam & 31, h = lam >> 5;
        uint4 v = *(const uint4*)&Lk[(e * 32 + l31) * 72 + ks * 16 + h * 8];
        *(uint4*)(kout + (size_t)pos * 8) = v;
    }
    // V fragments: 512 16B chunks, pos = (((e*2+ksl)*2+mt)*64 + lane)
    unsigned short* vout = vfo + (size_t)bh * PER_BH + (size_t)t * 4096;
    #pragma unroll
    for (int r = 0; r < 2; ++r) {
        int pos = r * 256 + tid;
        int lam = pos & 63, rest = pos >> 6;
        int e = rest >> 2, ksl = (rest >> 1) & 1, mt = rest & 1;
        int l31 = lam & 31, h = lam >> 5;
        int d  = mt * 32 + l31;
        int j0 = e * 32 + ksl * 16 + h * 8;
        union { unsigned short s[8]; uint4 u; } u;
        #pragma unroll
        for (int jj = 0; jj < 8; ++jj) u.s[jj] = Lv[(j0 + jj) * PSTR + d];
        *(uint4*)(vout + (size_t)pos * 8) = u.u;
    }
}

// ---------------- main kernel: no LDS, no barriers in the K-loop ----------------
__global__ __launch_bounds__(256, 4)
void poly_attn_main(const float* __restrict__ qg,
                    const unsigned short* __restrict__ kfo,
                    const unsigned short* __restrict__ vfo,
                    float* __restrict__ og)
{
    __shared__ float epb[4 * 32 * EPSTR];   // epilogue O^T partials
    __shared__ float dbuf[128];             // per-wave denominator partials

    const int tid  = threadIdx.x;
    const int lane = tid & 63;
    const int w    = tid >> 6;
    const int p    = w >> 1;      // pair id: Q rows [32p, 32p+32)
    const int e    = w & 1;       // j-half of each KV tile
    const int l31  = lane & 31;
    const int h    = lane >> 5;

    // XCD swizzle: id%8 selects XCD; give each XCD 4 bh's (2MB K+V working set in its L2)
    const int id = blockIdx.x;
    const int bh = (id & 7) * 4 + ((id >> 3) & 3);
    const int qt = id >> 5;
    const int q0 = qt * BQ;

    const float* qb = qg + ((size_t)bh * S_LEN + q0) * DH;
    const unsigned short* kw = kfo + (size_t)bh * PER_BH + e * 2048 + (size_t)lane * 8;
    const unsigned short* vw = vfo + (size_t)bh * PER_BH + e * 2048 + (size_t)lane * 8;
    float* ob = og + ((size_t)bh * S_LEN + q0) * DH;

    // ---- Q B-fragments: lane holds Q[q0 + 32p + l31][16ks + 8h + 0..7] ----
    bf16x8 qfrag[4];
    #pragma unroll
    for (int ks = 0; ks < 4; ++ks) {
        const float* qp = qb + (32 * p + l31) * DH + ks * 16 + h * 8;
        float4 f0 = *(const float4*)qp;
        float4 f1 = *(const float4*)(qp + 4);
        union { unsigned int d[4]; bf16x8 v; } u;
        u.d[0] = pack2bf(f0.x, f0.y);
        u.d[1] = pack2bf(f0.z, f0.w);
        u.d[2] = pack2bf(f1.x, f1.y);
        u.d[3] = pack2bf(f1.z, f1.w);
        qfrag[ks] = u.v;
    }

    f32x16 oacc[2];   // O^T[d = mt*32 + (r&3)+8*(r>>2)+4h][i = l31] partial over j-half
    #pragma unroll
    for (int mt = 0; mt < 2; ++mt)
        #pragma unroll
        for (int r = 0; r < 16; ++r) oacc[mt][r] = 0.f;
    float dsum = 0.f;

    uint4 kbuf[2][4], vbuf[2][4];
    #pragma unroll
    for (int x = 0; x < 4; ++x) {
        kbuf[0][x] = *(const uint4*)(kw + x * 512);
        vbuf[0][x] = *(const uint4*)(vw + x * 512);
    }

    // Per tile: (1) issue K(t+1), V(t+1) loads  (2) QK MFMAs on kbuf[cur]
    // (3) square/pack/permlane  (4) PV MFMAs on vbuf[cur].
    // All consumers wait on loads issued one full tile earlier (vmcnt(8)-style,
    // never a drain). (T+1)&31 wraps the tail prefetch in-bounds.
#define TILE_BODY(T, KCUR, KNXT, VCUR, VNXT)                                        \
    {                                                                               \
        const int tn_ = ((T) + 1) & 31;                                             \
        const unsigned short* kn_ = kw + (size_t)tn_ * 4096;                        \
        const unsigned short* vn_ = vw + (size_t)tn_ * 4096;                        \
        _Pragma("unroll")                                                           \
        for (int x = 0; x < 4; ++x) {                                               \
            KNXT[x] = *(const uint4*)(kn_ + x * 512);                               \
            VNXT[x] = *(const uint4*)(vn_ + x * 512);                               \
        }                                                                           \
        f32x16 acc;                                                                 \
        _Pragma("unroll")                                                           \
        for (int r = 0; r < 16; ++r) acc[r] = 0.f;                                  \
        _Pragma("unroll")                                                           \
        for (int ks = 0; ks < 4; ++ks) {                                            \
            union { uint4 u; bf16x8 v; } kc; kc.u = KCUR[ks];                       \
            acc = __builtin_amdgcn_mfma_f32_32x32x16_bf16(kc.v, qfrag[ks], acc, 0, 0, 0); \
        }                                                                           \
        unsigned int pk[4][2];                                                      \
        _Pragma("unroll")                                                           \
        for (int g = 0; g < 4; ++g) {                                               \
            float x0 = acc[4*g+0], x1 = acc[4*g+1], x2 = acc[4*g+2], x3 = acc[4*g+3]; \
            x0 *= x0; x1 *= x1; x2 *= x2; x3 *= x3;                                 \
            dsum += (x0 + x1) + (x2 + x3);                                          \
            pk[g][0] = pack2bf(x0, x1);                                             \
            pk[g][1] = pack2bf(x2, x3);                                             \
        }                                                                           \
        _Pragma("unroll")                                                           \
        for (int ksl = 0; ksl < 2; ++ksl) {                                         \
            unsigned int a0 = pk[2*ksl][0], b0 = pk[2*ksl+1][0];                    \
            unsigned int a1 = pk[2*ksl][1], b1 = pk[2*ksl+1][1];                    \
            pl32swap(a0, b0);                                                       \
            pl32swap(a1, b1);                                                       \
            union { unsigned int d[4]; bf16x8 v; } bu;                              \
            bu.d[0] = a0; bu.d[1] = a1; bu.d[2] = b0; bu.d[3] = b1;                 \
            _Pragma("unroll")                                                       \
            for (int mt = 0; mt < 2; ++mt) {                                        \
                union { uint4 u; bf16x8 v; } vv; vv.u = VCUR[ksl * 2 + mt];         \
                oacc[mt] = __builtin_amdgcn_mfma_f32_32x32x16_bf16(vv.v, bu.v, oacc[mt], 0, 0, 0); \
            }                                                                       \
        }                                                                           \
    }

    for (int tp = 0; tp < NT; tp += 2) {
        TILE_BODY(tp,     kbuf[0], kbuf[1], vbuf[0], vbuf[1]);
        TILE_BODY(tp + 1, kbuf[1], kbuf[0], vbuf[1], vbuf[0]);
    }
#undef TILE_BODY

    // ---- per-wave denominator partial for column i = l31 over its j-half ----
    float wavetot = dsum + __shfl_xor(dsum, 32);

    // ---- epilogue: write partials to LDS, combine wave pairs, store ----
    float* ep = epb + (size_t)w * (32 * EPSTR);
    #pragma unroll
    for (int mt = 0; mt < 2; ++mt) {
        #pragma unroll
        for (int g = 0; g < 4; ++g) {
            f32x4 vv;
            vv[0] = oacc[mt][4*g+0];
            vv[1] = oacc[mt][4*g+1];
            vv[2] = oacc[mt][4*g+2];
            vv[3] = oacc[mt][4*g+3];
            // O[i=l31][d = mt*32 + 8g + 4h + 0..3]
            *(f32x4*)&ep[l31 * EPSTR + mt * 32 + 8 * g + 4 * h] = vv;
        }
    }
    if (h == 0) dbuf[w * 32 + l31] = wavetot;
    __syncthreads();

    const float* ep0 = epb + (size_t)(2 * p)     * (32 * EPSTR);
    const float* ep1 = epb + (size_t)(2 * p + 1) * (32 * EPSTR);
    const int lrow = e * 16 + (lane >> 2);
    const float den = dbuf[2 * p * 32 + lrow] + dbuf[(2 * p + 1) * 32 + lrow];
    const float inv = 1.0f / fmaxf(den, 1e-4f);
    #pragma unroll
    for (int it = 0; it < 4; ++it) {
        int d0 = (lane & 3) * 16 + it * 4;
        f32x4 a = *(const f32x4*)&ep0[lrow * EPSTR + d0];
        f32x4 b = *(const f32x4*)&ep1[lrow * EPSTR + d0];
        f32x4 s;
        s[0] = (a[0] + b[0]) * inv;
        s[1] = (a[1] + b[1]) * inv;
        s[2] = (a[2] + b[2]) * inv;
        s[3] = (a[3] + b[3]) * inv;
        *(f32x4*)&ob[(32 * p + lrow) * DH + d0] = s;
    }
}

// ---------------- fallback (self-contained, used if ws too small) ----------------
#define LSTR 72
__global__ __launch_bounds__(256, 2)
void poly_attn_fallback(const float* __restrict__ qg, const float* __restrict__ kg,
                        const float* __restrict__ vg, float* __restrict__ og)
{
    __shared__ unsigned short Qs[64 * LSTR];
    __shared__ unsigned short Ksl[64 * LSTR];
    __shared__ unsigned short Vt[64 * LSTR];
    __shared__ unsigned short Xsl[64 * LSTR];

    const int tid  = threadIdx.x;
    const int lane = tid & 63;
    const int w    = tid >> 6;
    const int c    = lane & 15;
    const int quad = lane >> 4;
    const int i0   = w * 16;

    const int bh = blockIdx.y;
    const int q0 = blockIdx.x * 64;

    const float* qb = qg + ((size_t)bh * S_LEN + q0) * DH;
    const float* kb = kg + (size_t)bh * S_LEN * DH;
    const float* vb = vg + (size_t)bh * S_LEN * DH;
    float*       ob = og + ((size_t)bh * S_LEN + q0) * DH;

    {
        const float4* qf4 = (const float4*)qb;
        #pragma unroll
        for (int r = 0; r < 4; ++r) {
            int idx = r * 256 + tid;
            int row = idx >> 4, c4 = idx & 15;
            float4 f = qf4[idx];
            ushort4 hh;
            hh.x = f2bf(f.x); hh.y = f2bf(f.y); hh.z = f2bf(f.z); hh.w = f2bf(f.w);
            *(ushort4*)&Qs[row * LSTR + c4 * 4] = hh;
        }
    }

    f32x4 oacc[4];
    #pragma unroll
    for (int t = 0; t < 4; ++t) { oacc[t][0]=0.f; oacc[t][1]=0.f; oacc[t][2]=0.f; oacc[t][3]=0.f; }
    float dsum[4] = {0.f, 0.f, 0.f, 0.f};

    for (int t0 = 0; t0 < S_LEN; t0 += 64) {
        __syncthreads();
        {
            const float4* kf4 = (const float4*)(kb + (size_t)t0 * DH);
            const float4* vf4 = (const float4*)(vb + (size_t)t0 * DH);
            #pragma unroll
            for (int r = 0; r < 4; ++r) {
                int idx = r * 256 + tid;
                int row = idx >> 4, c4 = idx & 15;
                float4 f = kf4[idx];
                ushort4 hh;
                hh.x = f2bf(f.x); hh.y = f2bf(f.y); hh.z = f2bf(f.z); hh.w = f2bf(f.w);
                *(ushort4*)&Ksl[row * LSTR + c4 * 4] = hh;
                float4 g = vf4[idx];
                int d0 = c4 * 4;
                Vt[(d0 + 0) * LSTR + row] = f2bf(g.x);
                Vt[(d0 + 1) * LSTR + row] = f2bf(g.y);
                Vt[(d0 + 2) * LSTR + row] = f2bf(g.z);
                Vt[(d0 + 3) * LSTR + row] = f2bf(g.w);
            }
        }
        __syncthreads();

        f32x4 xacc[4];
        #pragma unroll
        for (int t = 0; t < 4; ++t) { xacc[t][0]=0.f; xacc[t][1]=0.f; xacc[t][2]=0.f; xacc[t][3]=0.f; }
        #pragma unroll
        for (int k0 = 0; k0 < 64; k0 += 32) {
            bf16x8 af = *(const bf16x8*)&Qs[(i0 + c) * LSTR + k0 + quad * 8];
            #pragma unroll
            for (int tn = 0; tn < 4; ++tn) {
                bf16x8 bfg = *(const bf16x8*)&Ksl[(tn * 16 + c) * LSTR + k0 + quad * 8];
                xacc[tn] = __builtin_amdgcn_mfma_f32_16x16x32_bf16(af, bfg, xacc[tn], 0, 0, 0);
            }
        }
        #pragma unroll
        for (int tn = 0; tn < 4; ++tn)
            #pragma unroll
            for (int r = 0; r < 4; ++r) {
                float xv = xacc[tn][r];
                float xs = xv * xv;
                dsum[r] += xs;
                Xsl[(i0 + quad * 4 + r) * LSTR + tn * 16 + c] = f2bf(xs);
            }
        __syncthreads();

        #pragma unroll
        for (int k0 = 0; k0 < 64; k0 += 32) {
            bf16x8 af = *(const bf16x8*)&Xsl[(i0 + c) * LSTR + k0 + quad * 8];
            #pragma unroll
            for (int tn = 0; tn < 4; ++tn) {
                bf16x8 bfg = *(const bf16x8*)&Vt[(tn * 16 + c) * LSTR + k0 + quad * 8];
                oacc[tn] = __builtin_amdgcn_mfma_f32_16x16x32_bf16(af, bfg, oacc[tn], 0, 0, 0);
            }
        }
    }

    #pragma unroll
    for (int r = 0; r < 4; ++r) {
        float s = dsum[r];
        s += __shfl_xor(s, 1);
        s += __shfl_xor(s, 2);
        s += __shfl_xor(s, 4);
        s += __shfl_xor(s, 8);
        dsum[r] = 1.0f / fmaxf(s, 1e-4f);
    }
    #pragma unroll
    for (int tn = 0; tn < 4; ++tn)
        #pragma unroll
        for (int r = 0; r < 4; ++r)
            ob[(i0 + quad * 4 + r) * DH + tn * 16 + c] = oacc[tn][r] * dsum[r];
}

extern "C" void kernel_launch(void* const* d_in, const int* in_sizes, int n_in,
                              void* d_out, int out_size, void* d_ws, size_t ws_size,
                              hipStream_t stream) {
    (void)in_sizes; (void)n_in; (void)out_size;
    const float* q = (const float*)d_in[0];
    const float* k = (const float*)d_in[1];
    const float* v = (const float*)d_in[2];
    float* o = (float*)d_out;

    const size_t elems = (size_t)BH_N * PER_BH;              // 4,194,304
    const size_t need  = 2 * elems * sizeof(unsigned short); // 16.78 MB

    if (ws_size >= need) {
        unsigned short* kfo = (unsigned short*)d_ws;
        unsigned short* vfo = kfo + elems;
        prepass_kernel<<<dim3(NT, BH_N), 256, 0, stream>>>(k, v, kfo, vfo);
        poly_attn_main<<<dim3(BH_N * S_LEN / BQ), 256, 0, stream>>>(q, kfo, vfo, o);
    } else {
        poly_attn_fallback<<<dim3(S_LEN / 64, BH_N), 256, 0, stream>>>(q, k, v, o);
    }
}

// Round 8
// 134.009 us; speedup vs baseline: 1.1878x; 1.0603x over previous
//
#include <hip/hip_runtime.h>

// PolynomialAttn: B=2,H=16,S=2048,D=64, degree=2, eps=1e-4, fp32 in/out.
// v8: v7 barrier-free fragment-stream loop, but each wave now computes TWO
// 32-row Q strips (64 rows) from the same K/V fragment loads => per-CU
// vector-memory traffic halves (the measured wall). BQ=128, grid 512,
// 2 blocks/CU. Packed-f32 (v_pk_*) square/denominator. Epilogue combines
// wave-pair j-halves through LDS.

#define S_LEN 2048
#define DH    64
#define BQ    128
#define BK    64
#define EPSTR 68        // epilogue fp32 stride
#define PSTR  65        // prepass V-transpose LDS stride
#define BH_N  32        // B*H
#define PER_BH (S_LEN * DH)   // 131072 elems
#define NT    (S_LEN / BK)    // 32 KV tiles

typedef __bf16 bf16x8 __attribute__((ext_vector_type(8)));
typedef __bf16 bf16x2 __attribute__((ext_vector_type(2)));
typedef float  f32x2  __attribute__((ext_vector_type(2)));
typedef float  f32x4  __attribute__((ext_vector_type(4)));
typedef float  f32x16 __attribute__((ext_vector_type(16)));
typedef unsigned int uivec2 __attribute__((ext_vector_type(2)));

__device__ __forceinline__ unsigned short f2bf(float f) {
    union { float f; unsigned int u; } x; x.f = f;
    unsigned int u = x.u;
    return (unsigned short)((u + 0x7fffu + ((u >> 16) & 1u)) >> 16);  // RNE
}

__device__ __forceinline__ unsigned int pack2bf(float lo, float hi) {
#if __has_builtin(__builtin_amdgcn_cvt_pk_bf16_f32)
    bf16x2 p = __builtin_amdgcn_cvt_pk_bf16_f32(lo, hi);
    union { bf16x2 v; unsigned int u; } c; c.v = p;
    return c.u;
#else
    return (unsigned int)f2bf(lo) | ((unsigned int)f2bf(hi) << 16);
#endif
}

__device__ __forceinline__ void pl32swap(unsigned int& a, unsigned int& b) {
#if __has_builtin(__builtin_amdgcn_permlane32_swap)
    uivec2 r = __builtin_amdgcn_permlane32_swap(a, b, false, false);
    a = r[0]; b = r[1];
#else
    asm("v_permlane32_swap_b32 %0, %1" : "+v"(a), "+v"(b));
#endif
}

// ---------------- prepass: K -> fragment-order bf16, V -> V^T fragment-order bf16 ----
// Kf layout (ushorts): [bh][t][e][ks][lane]*8 ; lane(l31,h) holds
//   K[bh][64t + 32e + l31][16ks + 8h + 0..7]
// Vf layout (ushorts): [bh][t][e][ksl][mt][lane]*8 ; lane(l31,h) holds
//   V^T[bh][mt*32 + l31][64t + 32e + 16ksl + 8h + 0..7]
__global__ __launch_bounds__(256)
void prepass_kernel(const float* __restrict__ kg, const float* __restrict__ vg,
                    unsigned short* __restrict__ kfo, unsigned short* __restrict__ vfo)
{
    __shared__ unsigned short Lk[64 * 72];
    __shared__ unsigned short Lv[64 * PSTR];
    const int tid = threadIdx.x;
    const int bh  = blockIdx.y;
    const int t   = blockIdx.x;
    const size_t base = (size_t)bh * PER_BH + (size_t)t * 64 * DH;

    const float4* kf4 = (const float4*)(kg + base);
    const float4* vf4 = (const float4*)(vg + base);
    #pragma unroll
    for (int r = 0; r < 4; ++r) {
        int idx = r * 256 + tid;              // float4 index in 64x64 tile
        int row = idx >> 4, c4 = idx & 15;
        float4 f = kf4[idx];
        ushort4 hh;
        hh.x = f2bf(f.x); hh.y = f2bf(f.y); hh.z = f2bf(f.z); hh.w = f2bf(f.w);
        *(ushort4*)&Lk[row * 72 + c4 * 4] = hh;
        float4 g = vf4[idx];
        unsigned short* pv = &Lv[row * PSTR + c4 * 4];
        pv[0] = f2bf(g.x); pv[1] = f2bf(g.y); pv[2] = f2bf(g.z); pv[3] = f2bf(g.w);
    }
    __syncthreads();

    unsigned short* kout = kfo + (size_t)bh * PER_BH + (size_t)t * 4096;
    #pragma unroll
    for (int r = 0; r < 2; ++r) {
        int pos = r * 256 + tid;
        int lam = pos & 63, rest = pos >> 6;
        int e = rest >> 2, ks = rest & 3;
        int l31 = lam & 31, h = lam >> 5;
        uint4 v = *(const uint4*)&Lk[(e * 32 + l31) * 72 + ks * 16 + h * 8];
        *(uint4*)(kout + (size_t)pos * 8) = v;
    }
    unsigned short* vout = vfo + (size_t)bh * PER_BH + (size_t)t * 4096;
    #pragma unroll
    for (int r = 0; r < 2; ++r) {
        int pos = r * 256 + tid;
        int lam = pos & 63, rest = pos >> 6;
        int e = rest >> 2, ksl = (rest >> 1) & 1, mt = rest & 1;
        int l31 = lam & 31, h = lam >> 5;
        int d  = mt * 32 + l31;
        int j0 = e * 32 + ksl * 16 + h * 8;
        union { unsigned short s[8]; uint4 u; } u;
        #pragma unroll
        for (int jj = 0; jj < 8; ++jj) u.s[jj] = Lv[(j0 + jj) * PSTR + d];
        *(uint4*)(vout + (size_t)pos * 8) = u.u;
    }
}

// ---------------- main kernel: 2 Q-strips per wave, no LDS/barriers in loop ----------------
__global__ __launch_bounds__(256, 2)
void poly_attn_main(const float* __restrict__ qg,
                    const unsigned short* __restrict__ kfo,
                    const unsigned short* __restrict__ vfo,
                    float* __restrict__ og)
{
    __shared__ float epb[8 * 32 * EPSTR];   // per (wave,strip) O^T partials
    __shared__ float dbuf[256];             // per (wave,strip) denominator partials

    const int tid  = threadIdx.x;
    const int lane = tid & 63;
    const int w    = tid >> 6;
    const int p    = w >> 1;      // pair id: Q rows [64p, 64p+64)
    const int e    = w & 1;       // j-half of each KV tile
    const int l31  = lane & 31;
    const int h    = lane >> 5;

    // XCD swizzle: id%8 -> XCD; 4 bh per XCD (K+V 2MB working set in its L2)
    const int id = blockIdx.x;
    const int r5 = id & 31;
    const int bh = (r5 & 7) * 4 + (r5 >> 3);
    const int qt = id >> 5;
    const int q0 = qt * BQ;

    const float* qb = qg + ((size_t)bh * S_LEN + q0) * DH;
    const unsigned short* kw = kfo + (size_t)bh * PER_BH + e * 2048 + (size_t)lane * 8;
    const unsigned short* vw = vfo + (size_t)bh * PER_BH + e * 2048 + (size_t)lane * 8;
    float* ob = og + ((size_t)bh * S_LEN + q0) * DH;

    // ---- Q B-fragments: strip s rows 64p + 32s + l31, cols 16ks + 8h + 0..7 ----
    bf16x8 qfrag[2][4];
    #pragma unroll
    for (int s = 0; s < 2; ++s) {
        #pragma unroll
        for (int ks = 0; ks < 4; ++ks) {
            const float* qp = qb + (64 * p + 32 * s + l31) * DH + ks * 16 + h * 8;
            float4 f0 = *(const float4*)qp;
            float4 f1 = *(const float4*)(qp + 4);
            union { unsigned int d[4]; bf16x8 v; } u;
            u.d[0] = pack2bf(f0.x, f0.y);
            u.d[1] = pack2bf(f0.z, f0.w);
            u.d[2] = pack2bf(f1.x, f1.y);
            u.d[3] = pack2bf(f1.z, f1.w);
            qfrag[s][ks] = u.v;
        }
    }

    f32x16 oacc[2][2];   // [strip][mt]: O^T[d=mt*32+(r&3)+8(r>>2)+4h][i=l31] j-half partial
    #pragma unroll
    for (int s = 0; s < 2; ++s)
        #pragma unroll
        for (int mt = 0; mt < 2; ++mt)
            #pragma unroll
            for (int r = 0; r < 16; ++r) oacc[s][mt][r] = 0.f;
    f32x2 ds2[2];
    ds2[0][0]=0.f; ds2[0][1]=0.f; ds2[1][0]=0.f; ds2[1][1]=0.f;

    uint4 kbuf[2][4], vbuf[2][4];
    #pragma unroll
    for (int x = 0; x < 4; ++x) {
        kbuf[0][x] = *(const uint4*)(kw + x * 512);
        vbuf[0][x] = *(const uint4*)(vw + x * 512);
    }

    // Per tile: issue t+1 loads; QK both strips (shared K frags); packed-f32
    // square + denom; permlane C->B; PV both strips (shared V frags).
#define TILE_BODY(T, KCUR, KNXT, VCUR, VNXT)                                        \
    {                                                                               \
        const int tn_ = ((T) + 1) & 31;                                             \
        const unsigned short* kn_ = kw + (size_t)tn_ * 4096;                        \
        const unsigned short* vn_ = vw + (size_t)tn_ * 4096;                        \
        _Pragma("unroll")                                                           \
        for (int x = 0; x < 4; ++x) {                                               \
            KNXT[x] = *(const uint4*)(kn_ + x * 512);                               \
            VNXT[x] = *(const uint4*)(vn_ + x * 512);                               \
        }                                                                           \
        f32x16 acc0, acc1;                                                          \
        _Pragma("unroll")                                                           \
        for (int r = 0; r < 16; ++r) { acc0[r] = 0.f; acc1[r] = 0.f; }              \
        _Pragma("unroll")                                                           \
        for (int ks = 0; ks < 4; ++ks) {                                            \
            union { uint4 u; bf16x8 v; } kc; kc.u = KCUR[ks];                       \
            acc0 = __builtin_amdgcn_mfma_f32_32x32x16_bf16(kc.v, qfrag[0][ks], acc0, 0, 0, 0); \
            acc1 = __builtin_amdgcn_mfma_f32_32x32x16_bf16(kc.v, qfrag[1][ks], acc1, 0, 0, 0); \
        }                                                                           \
        _Pragma("unroll")                                                           \
        for (int s = 0; s < 2; ++s) {                                               \
            unsigned int pk[4][2];                                                  \
            _Pragma("unroll")                                                       \
            for (int g = 0; g < 4; ++g) {                                           \
                f32x2 v01, v23;                                                     \
                v01[0] = (s ? acc1 : acc0)[4*g+0]; v01[1] = (s ? acc1 : acc0)[4*g+1]; \
                v23[0] = (s ? acc1 : acc0)[4*g+2]; v23[1] = (s ? acc1 : acc0)[4*g+3]; \
                v01 = v01 * v01; v23 = v23 * v23;                                   \
                ds2[s] += v01; ds2[s] += v23;                                       \
                pk[g][0] = pack2bf(v01[0], v01[1]);                                 \
                pk[g][1] = pack2bf(v23[0], v23[1]);                                 \
            }                                                                       \
            _Pragma("unroll")                                                       \
            for (int ksl = 0; ksl < 2; ++ksl) {                                     \
                unsigned int a0 = pk[2*ksl][0], b0 = pk[2*ksl+1][0];                \
                unsigned int a1 = pk[2*ksl][1], b1 = pk[2*ksl+1][1];                \
                pl32swap(a0, b0);                                                   \
                pl32swap(a1, b1);                                                   \
                union { unsigned int d[4]; bf16x8 v; } bu;                          \
                bu.d[0] = a0; bu.d[1] = a1; bu.d[2] = b0; bu.d[3] = b1;             \
                _Pragma("unroll")                                                   \
                for (int mt = 0; mt < 2; ++mt) {                                    \
                    union { uint4 u; bf16x8 v; } vv; vv.u = VCUR[ksl * 2 + mt];     \
                    oacc[s][mt] = __builtin_amdgcn_mfma_f32_32x32x16_bf16(vv.v, bu.v, oacc[s][mt], 0, 0, 0); \
                }                                                                   \
            }                                                                       \
        }                                                                           \
    }

    for (int tp = 0; tp < NT; tp += 2) {
        TILE_BODY(tp,     kbuf[0], kbuf[1], vbuf[0], vbuf[1]);
        TILE_BODY(tp + 1, kbuf[1], kbuf[0], vbuf[1], vbuf[0]);
    }
#undef TILE_BODY

    // ---- denominator partials (column i = l31, this wave's j-half, per strip) ----
    float wavetot[2];
    #pragma unroll
    for (int s = 0; s < 2; ++s) {
        float t = ds2[s][0] + ds2[s][1];
        wavetot[s] = t + __shfl_xor(t, 32);
    }

    // ---- epilogue: stash partials, combine wave-pair j-halves, store ----
    #pragma unroll
    for (int s = 0; s < 2; ++s) {
        float* ep = epb + (size_t)(w * 2 + s) * (32 * EPSTR);
        #pragma unroll
        for (int mt = 0; mt < 2; ++mt) {
            #pragma unroll
            for (int g = 0; g < 4; ++g) {
                f32x4 vv;
                vv[0] = oacc[s][mt][4*g+0];
                vv[1] = oacc[s][mt][4*g+1];
                vv[2] = oacc[s][mt][4*g+2];
                vv[3] = oacc[s][mt][4*g+3];
                // O[i=l31][d = mt*32 + 8g + 4h + 0..3]
                *(f32x4*)&ep[l31 * EPSTR + mt * 32 + 8 * g + 4 * h] = vv;
            }
        }
        if (h == 0) dbuf[(w * 2 + s) * 32 + l31] = wavetot[s];
    }
    __syncthreads();

    // wave w handles output rows [32w, 32w+32): p_src = w>>1, s_src = w&1
    const int psrc = w >> 1, ssrc = w & 1;
    const int r0 = (2 * psrc + 0) * 2 + ssrc;   // e=0 partial region
    const int r1 = (2 * psrc + 1) * 2 + ssrc;   // e=1 partial region
    const int lr = lane >> 1;
    const float den = dbuf[r0 * 32 + lr] + dbuf[r1 * 32 + lr];
    const float inv = 1.0f / fmaxf(den, 1e-4f);
    const float* ea = epb + (size_t)r0 * (32 * EPSTR) + lr * EPSTR;
    const float* eb = epb + (size_t)r1 * (32 * EPSTR) + lr * EPSTR;
    #pragma unroll
    for (int it = 0; it < 8; ++it) {
        int d0 = (lane & 1) * 32 + it * 4;
        f32x4 a = *(const f32x4*)&ea[d0];
        f32x4 b = *(const f32x4*)&eb[d0];
        f32x4 sm;
        sm[0] = (a[0] + b[0]) * inv;
        sm[1] = (a[1] + b[1]) * inv;
        sm[2] = (a[2] + b[2]) * inv;
        sm[3] = (a[3] + b[3]) * inv;
        *(f32x4*)&ob[(32 * w + lr) * DH + d0] = sm;
    }
}

// ---------------- fallback (self-contained, used if ws too small) ----------------
#define LSTR 72
__global__ __launch_bounds__(256, 2)
void poly_attn_fallback(const float* __restrict__ qg, const float* __restrict__ kg,
                        const float* __restrict__ vg, float* __restrict__ og)
{
    __shared__ unsigned short Qs[64 * LSTR];
    __shared__ unsigned short Ksl[64 * LSTR];
    __shared__ unsigned short Vt[64 * LSTR];
    __shared__ unsigned short Xsl[64 * LSTR];

    const int tid  = threadIdx.x;
    const int lane = tid & 63;
    const int w    = tid >> 6;
    const int c    = lane & 15;
    const int quad = lane >> 4;
    const int i0   = w * 16;

    const int bh = blockIdx.y;
    const int q0 = blockIdx.x * 64;

    const float* qb = qg + ((size_t)bh * S_LEN + q0) * DH;
    const float* kb = kg + (size_t)bh * S_LEN * DH;
    const float* vb = vg + (size_t)bh * S_LEN * DH;
    float*       ob = og + ((size_t)bh * S_LEN + q0) * DH;

    {
        const float4* qf4 = (const float4*)qb;
        #pragma unroll
        for (int r = 0; r < 4; ++r) {
            int idx = r * 256 + tid;
            int row = idx >> 4, c4 = idx & 15;
            float4 f = qf4[idx];
            ushort4 hh;
            hh.x = f2bf(f.x); hh.y = f2bf(f.y); hh.z = f2bf(f.z); hh.w = f2bf(f.w);
            *(ushort4*)&Qs[row * LSTR + c4 * 4] = hh;
        }
    }

    f32x4 oacc[4];
    #pragma unroll
    for (int t = 0; t < 4; ++t) { oacc[t][0]=0.f; oacc[t][1]=0.f; oacc[t][2]=0.f; oacc[t][3]=0.f; }
    float dsum[4] = {0.f, 0.f, 0.f, 0.f};

    for (int t0 = 0; t0 < S_LEN; t0 += 64) {
        __syncthreads();
        {
            const float4* kf4 = (const float4*)(kb + (size_t)t0 * DH);
            const float4* vf4 = (const float4*)(vb + (size_t)t0 * DH);
            #pragma unroll
            for (int r = 0; r < 4; ++r) {
                int idx = r * 256 + tid;
                int row = idx >> 4, c4 = idx & 15;
                float4 f = kf4[idx];
                ushort4 hh;
                hh.x = f2bf(f.x); hh.y = f2bf(f.y); hh.z = f2bf(f.z); hh.w = f2bf(f.w);
                *(ushort4*)&Ksl[row * LSTR + c4 * 4] = hh;
                float4 g = vf4[idx];
                int d0 = c4 * 4;
                Vt[(d0 + 0) * LSTR + row] = f2bf(g.x);
                Vt[(d0 + 1) * LSTR + row] = f2bf(g.y);
                Vt[(d0 + 2) * LSTR + row] = f2bf(g.z);
                Vt[(d0 + 3) * LSTR + row] = f2bf(g.w);
            }
        }
        __syncthreads();

        f32x4 xacc[4];
        #pragma unroll
        for (int t = 0; t < 4; ++t) { xacc[t][0]=0.f; xacc[t][1]=0.f; xacc[t][2]=0.f; xacc[t][3]=0.f; }
        #pragma unroll
        for (int k0 = 0; k0 < 64; k0 += 32) {
            bf16x8 af = *(const bf16x8*)&Qs[(i0 + c) * LSTR + k0 + quad * 8];
            #pragma unroll
            for (int tn = 0; tn < 4; ++tn) {
                bf16x8 bfg = *(const bf16x8*)&Ksl[(tn * 16 + c) * LSTR + k0 + quad * 8];
                xacc[tn] = __builtin_amdgcn_mfma_f32_16x16x32_bf16(af, bfg, xacc[tn], 0, 0, 0);
            }
        }
        #pragma unroll
        for (int tn = 0; tn < 4; ++tn)
            #pragma unroll
            for (int r = 0; r < 4; ++r) {
                float xv = xacc[tn][r];
                float xs = xv * xv;
                dsum[r] += xs;
                Xsl[(i0 + quad * 4 + r) * LSTR + tn * 16 + c] = f2bf(xs);
            }
        __syncthreads();

        #pragma unroll
        for (int k0 = 0; k0 < 64; k0 += 32) {
            bf16x8 af = *(const bf16x8*)&Xsl[(i0 + c) * LSTR + k0 + quad * 8];
            #pragma unroll
            for (int tn = 0; tn < 4; ++tn) {
                bf16x8 bfg = *(const bf16x8*)&Vt[(tn * 16 + c) * LSTR + k0 + quad * 8];
                oacc[tn] = __builtin_amdgcn_mfma_f32_16x16x32_bf16(af, bfg, oacc[tn], 0, 0, 0);
            }
        }
    }

    #pragma unroll
    for (int r = 0; r < 4; ++r) {
        float s = dsum[r];
        s += __shfl_xor(s, 1);
        s += __shfl_xor(s, 2);
        s += __shfl_xor(s, 4);
        s += __shfl_xor(s, 8);
        dsum[r] = 1.0f / fmaxf(s, 1e-4f);
    }
    #pragma unroll
    for (int tn = 0; tn < 4; ++tn)
        #pragma unroll
        for (int r = 0; r < 4; ++r)
            ob[(i0 + quad * 4 + r) * DH + tn * 16 + c] = oacc[tn][r] * dsum[r];
}

extern "C" void kernel_launch(void* const* d_in, const int* in_sizes, int n_in,
                              void* d_out, int out_size, void* d_ws, size_t ws_size,
                              hipStream_t stream) {
    (void)in_sizes; (void)n_in; (void)out_size;
    const float* q = (const float*)d_in[0];
    const float* k = (const float*)d_in[1];
    const float* v = (const float*)d_in[2];
    float* o = (float*)d_out;

    const size_t elems = (size_t)BH_N * PER_BH;              // 4,194,304
    const size_t need  = 2 * elems * sizeof(unsigned short); // 16.78 MB

    if (ws_size >= need) {
        unsigned short* kfo = (unsigned short*)d_ws;
        unsigned short* vfo = kfo + elems;
        prepass_kernel<<<dim3(NT, BH_N), 256, 0, stream>>>(k, v, kfo, vfo);
        poly_attn_main<<<dim3(BH_N * S_LEN / BQ), 256, 0, stream>>>(q, kfo, vfo, o);
    } else {
        poly_attn_fallback<<<dim3(S_LEN / 64, BH_N), 256, 0, stream>>>(q, k, v, o);
    }
}